// Round 8
// baseline (433.237 us; speedup 1.0000x reference)
//
#include <hip/hip_runtime.h>
#include <hip/hip_bf16.h>
#include <stdint.h>

typedef __hip_bfloat16 bf16;
typedef __attribute__((ext_vector_type(8))) short short8;
typedef __attribute__((ext_vector_type(4))) short short4v;
typedef __attribute__((ext_vector_type(4))) float f32x4;

constexpr int cB = 16384, cD = 512, cH = 1024, cS = 8, cE = 4, cDH = 256;

__device__ __forceinline__ float tof(bf16 v) { return __bfloat162float(v); }
__device__ __forceinline__ bf16 tob(float v) { return __float2bfloat16(v); }
__device__ __forceinline__ float b2f(short s) {
  uint32_t u = ((uint32_t)(uint16_t)s) << 16;
  return __builtin_bit_cast(float, u);
}
__device__ __forceinline__ float ldf(const void* p, long i, int isbf) {
  return isbf ? b2f(((const short*)p)[i]) : ((const float*)p)[i];
}
__device__ __forceinline__ void stbf_nt(bf16* p, float v) {
  __builtin_nontemporal_store(__builtin_bit_cast(short, tob(v)), (short*)p);
}

__device__ __forceinline__ void gload_lds16(const bf16* g, char* l) {
  __builtin_amdgcn_global_load_lds(
      (const __attribute__((address_space(1))) void*)g,
      (__attribute__((address_space(3))) void*)l, 16, 0, 0);
}

// ---- dtype probe ----
__global__ __launch_bounds__(256) void probe_k(const void* x, int* flag) {
  __shared__ int sh[256];
  const unsigned short* u = (const unsigned short*)x;
  int cnt = 0;
  for (int i = threadIdx.x; i < 2048; i += 256) {
    float v = fabsf(b2f((short)u[2 * i]));
    cnt += (v > 1e-5f && v < 1e3f) ? 1 : 0;
  }
  sh[threadIdx.x] = cnt;
  __syncthreads();
  for (int s = 128; s > 0; s >>= 1) {
    if (threadIdx.x < s) sh[threadIdx.x] += sh[threadIdx.x + s];
    __syncthreads();
  }
  if (threadIdx.x == 0) flag[0] = (sh[0] > 1024) ? 1 : 0;
}

__global__ __launch_bounds__(256) void cvtx_k(const void* x, bf16* xb, const int* flag) {
  int g = blockIdx.x * 256 + threadIdx.x;
  if (flag[0]) {
    ((short8*)xb)[g] = ((const short8*)x)[g];
  } else {
    const f32x4* xf = (const f32x4*)x;
    f32x4 v0 = xf[2 * g], v1 = xf[2 * g + 1];
    short8 o;
#pragma unroll
    for (int j = 0; j < 4; j++) {
      o[j] = __builtin_bit_cast(short, tob(v0[j]));
      o[j + 4] = __builtin_bit_cast(short, tob(v1[j]));
    }
    ((short8*)xb)[g] = o;
  }
}

struct CvtDesc {
  const void* src[11];
  int off[12];
};
__global__ __launch_bounds__(256) void cvt_smalls_k(CvtDesc d, const int* flag, float* dst) {
  int i = blockIdx.x * 256 + threadIdx.x;
  if (i >= d.off[11]) return;
  int isb = flag[0];
  int j = 0;
  while (i >= d.off[j + 1]) j++;
  dst[i] = ldf(d.src[j], i - d.off[j], isb);
}

__global__ __launch_bounds__(256) void transpose_k(const void* in, bf16* out, int ldin, int ldout,
                                                   long in_off, long in_bs, long out_bs,
                                                   const int* flag) {
  __shared__ float tile[32][33];
  int isb = flag[0];
  long src0 = in_off + (long)blockIdx.z * in_bs;
  bf16* dst = out + (long)blockIdx.z * out_bs;
  int c0 = blockIdx.x * 32, r0 = blockIdx.y * 32;
  int tx = threadIdx.x & 31, ty = threadIdx.x >> 5;
#pragma unroll
  for (int i = 0; i < 4; i++)
    tile[ty + i * 8][tx] = ldf(in, src0 + (long)(r0 + ty + i * 8) * ldin + c0 + tx, isb);
  __syncthreads();
#pragma unroll
  for (int i = 0; i < 4; i++)
    dst[(long)(c0 + ty + i * 8) * ldout + r0 + tx] = tob(tile[tx][ty + i * 8]);
}

// ---- out_w -> owpair: interleaved [W0;W2]^T / [W1;W3]^T rows (EPI9 pairing) ----
__global__ __launch_bounds__(256) void owt_k(const void* ow, bf16* owpair, const int* flag) {
  __shared__ float tile[32][33];
  int isb = flag[0];
  int z = blockIdx.z;
  int m = z & 1, kb = (z >> 1) * 512;
  long base = (long)z * 512 * cD;
  int c0 = blockIdx.x * 32, r0 = blockIdx.y * 32;
  int tx = threadIdx.x & 31, ty = threadIdx.x >> 5;
#pragma unroll
  for (int i = 0; i < 4; i++)
    tile[ty + i * 8][tx] = ldf(ow, base + (long)(r0 + ty + i * 8) * cD + c0 + tx, isb);
  __syncthreads();
#pragma unroll
  for (int i = 0; i < 4; i++) {
    int n = c0 + ty + i * 8;
    int R = ((n >> 6) << 7) + (((n >> 5) & 1) << 6) + (m << 5) + (((n >> 4) & 1) << 4) + (n & 15);
    owpair[(long)R * 1024 + kb + r0 + tx] = tob(tile[tx][ty + i * 8]);
  }
}

// ================  BMx128 GEMM engine (BM = 128 or 64)  ================
// EPI: 1 relu(acc+bias)->bf16 [nt] ; 2 C(f32) (=/+=) gates*(acc+bias)
//      3 C(f32)=acc ; 4 (acc+bias)->bf16 ; 6 gates[b,n>>10]*relu(acc+bias)->bf16 [nt]
//      7 acc + gates[b,:]·b2[:,n] -> bf16 ; 9 merged: acc1 + wsel*acc2 + bias -> out
struct GArgs {
  const bf16* A; int lda;
  const bf16* Bt; int ldb; long bt_stride;
  void* C; int ldc;
  int M, N, K;
  const float* bias; int bias_stride;
  const float* gates; int eidx;
  const int* perm; const int* cum;
  const float* wsel;
  const int* dflag;
};

template <int EPI, bool GROUPED, bool GATHER_A, bool SCATTER_C, int BM = 128>
__global__ __launch_bounds__(256, 4) void gemm_k(GArgs a) {
  constexpr int MI = BM / 32;        // acc rows per wave (4 or 2)
  constexpr int NCA = BM / 32;       // A staging calls per wave (4 or 2)
  __shared__ char smem[BM * 128 + 16384];
  char* ldsA = smem;
  char* ldsB = smem + BM * 128;

  int bxs, bys;
  if constexpr (!GROUPED) {
    // XCD-aware bijective remap (T1/m204); grouped kernels keep identity
    // (early-exit would concentrate live blocks on XCD0 — r4 post-mortem).
    const int gx = gridDim.x;
    const int nwg = gx * gridDim.y;
    const int d = blockIdx.y * gx + blockIdx.x;
    const int q = nwg >> 3, r = nwg & 7;
    const int xcd = d & 7, di = d >> 3;
    const int logical = (xcd < r ? xcd * (q + 1) : r * (q + 1) + (xcd - r) * q) + di;
    bxs = logical % gx;
    bys = logical / gx;
  } else {
    bxs = blockIdx.x;
    bys = blockIdx.y;
  }

  int g0, cnt;
  if constexpr (GROUPED) {
    int z = blockIdx.z;
    g0 = a.cum[z];
    cnt = a.cum[z + 1] - g0;
  } else {
    g0 = 0;
    cnt = a.M;
  }
  const int ptile = bys * BM;
  if (ptile >= cnt) return;
  const int n0 = bxs * 128;

  const int t = threadIdx.x, w = t >> 6, l = t & 63;
  const int wm = w >> 1, wn = w & 1;

  const bf16* bt = a.Bt + (GROUPED ? (long)blockIdx.z * a.bt_stride : 0);
  const float* bias = a.bias ? (a.bias + (GROUPED ? blockIdx.z * a.bias_stride : 0)) : nullptr;

  const bf16* aSrc[NCA];
  const bf16* bSrc[4];
  int ldsOffA[NCA];
  int ldsOffB[4];
#pragma unroll
  for (int c = 0; c < NCA; c++) {
    int pos = w * (BM * 32) + c * 1024 + l * 16;    // byte pos in A tile (BM*128 B)
    int row = pos >> 7;                             // 128B per row (64 bf16)
    int su = ((((pos >> 4) & 7) ^ (row & 7))) * 8;  // swizzled source k-offset
    int p = ptile + row;
    if (p > cnt - 1) p = cnt - 1;
    int ar;
    if constexpr (GATHER_A) ar = a.perm[g0 + p];
    else ar = g0 + p;
    aSrc[c] = a.A + (long)ar * a.lda + su;
    ldsOffA[c] = w * (BM * 32) + c * 1024;
  }
#pragma unroll
  for (int c = 0; c < 4; c++) {
    int pos = w * 4096 + c * 1024 + l * 16;
    int row = pos >> 7;
    int su = ((((pos >> 4) & 7) ^ (row & 7))) * 8;
    bSrc[c] = bt + (long)(n0 + row) * a.ldb + su;
    ldsOffB[c] = w * 4096 + c * 1024;
  }

  f32x4 zero = {0.f, 0.f, 0.f, 0.f};
  f32x4 acc[MI][4];
#pragma unroll
  for (int i = 0; i < MI; i++)
#pragma unroll
    for (int j = 0; j < 4; j++) acc[i][j] = zero;

  const int nkt = a.K >> 6;
  for (int kt = 0; kt < nkt; ++kt) {
#pragma unroll
    for (int c = 0; c < NCA; c++) gload_lds16(aSrc[c] + kt * 64, ldsA + ldsOffA[c]);
#pragma unroll
    for (int c = 0; c < 4; c++) gload_lds16(bSrc[c] + kt * 64, ldsB + ldsOffB[c]);
    __syncthreads();
#pragma unroll
    for (int kk = 0; kk < 2; kk++) {
      short8 af[MI], bv[4];
#pragma unroll
      for (int mi = 0; mi < MI; mi++) {
        int row = wm * (BM / 2) + mi * 16 + (l & 15);
        int kg = kk * 4 + (l >> 4);
        int off = row * 128 + ((kg ^ (row & 7)) << 4);
        af[mi] = *(const short8*)(ldsA + off);
      }
#pragma unroll
      for (int ni = 0; ni < 4; ni++) {
        int row = wn * 64 + ni * 16 + (l & 15);
        int kg = kk * 4 + (l >> 4);
        int off = row * 128 + ((kg ^ (row & 7)) << 4);
        bv[ni] = *(const short8*)(ldsB + off);
      }
#pragma unroll
      for (int mi = 0; mi < MI; mi++)
#pragma unroll
        for (int ni = 0; ni < 4; ni++)
          acc[mi][ni] =
              __builtin_amdgcn_mfma_f32_16x16x32_bf16(af[mi], bv[ni], acc[mi][ni], 0, 0, 0);
    }
    __syncthreads();
  }

  const int l15 = l & 15, lg4 = l >> 4;
  int outbf = 1;
  if constexpr (EPI == 9) outbf = a.dflag[0];
#pragma unroll
  for (int mi = 0; mi < MI; mi++) {
#pragma unroll
    for (int j = 0; j < 4; j++) {
      int p = ptile + wm * (BM / 2) + mi * 16 + lg4 * 4 + j;
      if (p >= cnt) continue;
      int crow;
      if constexpr (SCATTER_C) crow = a.perm[g0 + p];
      else crow = g0 + p;
      if constexpr (EPI == 9) {
        float wv = a.wsel[crow];
#pragma unroll
        for (int ni = 0; ni < 2; ni++) {
          int n = (n0 >> 1) + wn * 32 + ni * 16 + l15;
          float o = acc[mi][ni][j] + wv * acc[mi][ni + 2][j] + a.bias[n];
          if (outbf) ((bf16*)a.C)[(long)crow * a.ldc + n] = tob(o);
          else ((float*)a.C)[(long)crow * a.ldc + n] = o;
        }
        continue;
      }
#pragma unroll
      for (int ni = 0; ni < 4; ni++) {
        int n = n0 + wn * 64 + ni * 16 + l15;
        float v = acc[mi][ni][j];
        if constexpr (EPI == 1) {
          v += bias[n];
          v = fmaxf(v, 0.f);
          stbf_nt(&((bf16*)a.C)[(long)crow * a.ldc + n], v);
        } else if constexpr (EPI == 2) {
          float g = a.gates[(long)(g0 + p) * 4 + a.eidx];
          v = g * (v + bias[n]);
          float* Cf = (float*)a.C;
          long idx = (long)crow * a.ldc + n;
          if (a.eidx == 0) Cf[idx] = v;
          else Cf[idx] += v;
        } else if constexpr (EPI == 3) {
          ((float*)a.C)[(long)crow * a.ldc + n] = v;
        } else if constexpr (EPI == 4) {
          v += bias[n];
          ((bf16*)a.C)[(long)crow * a.ldc + n] = tob(v);
        } else if constexpr (EPI == 6) {
          float g = a.gates[(long)(g0 + p) * 4 + (n >> 10)];
          v = g * fmaxf(v + bias[n], 0.f);
          stbf_nt(&((bf16*)a.C)[(long)crow * a.ldc + n], v);
        } else if constexpr (EPI == 7) {
          const float* gr = a.gates + (long)(g0 + p) * 4;
          v += gr[0] * bias[n] + gr[1] * bias[512 + n] + gr[2] * bias[1024 + n] +
               gr[3] * bias[1536 + n];
          ((bf16*)a.C)[(long)crow * a.ldc + n] = tob(v);
        }
      }
    }
  }
}

// =====================  small kernels  =====================
__global__ __launch_bounds__(256) void gates_k(const bf16* x, const float* gw, const float* gb,
                                               float* gates) {
  int b = blockIdx.x * 4 + (threadIdx.x >> 6);
  int l = threadIdx.x & 63;
  short8 xv = *(const short8*)(x + (long)b * cD + l * 8);
  float a0 = 0, a1 = 0, a2 = 0, a3 = 0;
#pragma unroll
  for (int j = 0; j < 8; j++) {
    float xf = b2f(xv[j]);
    f32x4 wr = *(const f32x4*)(gw + (l * 8 + j) * 4);
    a0 += xf * wr[0];
    a1 += xf * wr[1];
    a2 += xf * wr[2];
    a3 += xf * wr[3];
  }
#pragma unroll
  for (int o = 32; o > 0; o >>= 1) {
    a0 += __shfl_xor(a0, o);
    a1 += __shfl_xor(a1, o);
    a2 += __shfl_xor(a2, o);
    a3 += __shfl_xor(a3, o);
  }
  a0 += gb[0];
  a1 += gb[1];
  a2 += gb[2];
  a3 += gb[3];
  float m = fmaxf(fmaxf(a0, a1), fmaxf(a2, a3));
  float e0 = expf(a0 - m), e1 = expf(a1 - m), e2 = expf(a2 - m), e3 = expf(a3 - m);
  float s = e0 + e1 + e2 + e3;
  if (l == 0) {
    float* gp = gates + (long)b * 4;
    gp[0] = e0 / s;
    gp[1] = e1 / s;
    gp[2] = e2 / s;
    gp[3] = e3 / s;
  }
}

__global__ __launch_bounds__(256) void bhist_k(const int* sid, int* bh) {
  int blk = blockIdx.x, t = threadIdx.x;
  __shared__ int h[cS];
  if (t < cS) h[t] = 0;
  __syncthreads();
  int s = sid[blk * 256 + t];
#pragma unroll
  for (int q = 0; q < cS; q++) {
    unsigned long long m = __ballot(s == q);
    if ((t & 63) == 0) atomicAdd(&h[q], __popcll(m));
  }
  __syncthreads();
  if (t < cS) bh[blk * cS + t] = h[t];
}

__global__ void bbase_k(const int* bh, int* base, int* cum) {
  __shared__ int tot[cS];
  int s = threadIdx.x;
  if (s < cS) {
    int run = 0;
    for (int b = 0; b < 64; b++) {
      base[b * cS + s] = run;
      run += bh[b * cS + s];
    }
    tot[s] = run;
  }
  __syncthreads();
  if (s == 0) {
    int run = 0;
    for (int q = 0; q < cS; q++) {
      cum[q] = run;
      run += tot[q];
    }
    cum[cS] = run;
  }
  __syncthreads();
  if (s < cS) {
    int c = cum[s];
    for (int b = 0; b < 64; b++) base[b * cS + s] += c;
  }
}

__global__ __launch_bounds__(256) void bscat_k(const int* sid, const int* base, int* perm) {
  int blk = blockIdx.x, t = threadIdx.x, w = t >> 6, l = t & 63;
  __shared__ int wc[4][cS];
  __shared__ int wb[4][cS];
  int s = sid[blk * 256 + t];
  int rank = 0;
#pragma unroll
  for (int q = 0; q < cS; q++) {
    unsigned long long m = __ballot(s == q);
    if (l == 0) wc[w][q] = __popcll(m);
    if (s == q) rank = __popcll(m & ((1ull << l) - 1ull));
  }
  __syncthreads();
  if (t < cS) {
    int run = 0;
#pragma unroll
    for (int ww = 0; ww < 4; ww++) {
      wb[ww][t] = run;
      run += wc[ww][t];
    }
  }
  __syncthreads();
  perm[base[blk * cS + s] + wb[w][s] + rank] = blk * 256 + t;
}

__global__ __launch_bounds__(256) void scenpart_k(const float* emb, const float* w1,
                                                  const float* b1, float* scp) {
  __shared__ float red[8][32];
  int s = blockIdx.x;
  int nl = threadIdx.x & 31;
  int n = blockIdx.y * 32 + nl;
  int dg = threadIdx.x >> 5;
  float a = 0.f;
#pragma unroll 4
  for (int d = dg * 64; d < dg * 64 + 64; d++) a += emb[s * cD + d] * w1[(long)(cD + d) * cDH + n];
  red[dg][nl] = a;
  __syncthreads();
  if (dg == 0) {
    float t = b1[n];
#pragma unroll
    for (int g = 0; g < 8; g++) t += red[g][nl];
    scp[s * cDH + n] = t;
  }
}

__global__ __launch_bounds__(256) void wsel_k(const float* sp, const float* scp, const float* w2,
                                              const int* sid, float* wsel) {
  int b = blockIdx.x * 4 + (threadIdx.x >> 6);
  int l = threadIdx.x & 63;
  float spv[4], w2v[4];
#pragma unroll
  for (int q = 0; q < 4; q++) {
    spv[q] = sp[(long)b * cDH + q * 64 + l];
    w2v[q] = w2[q * 64 + l];
  }
  float lg[8];
#pragma unroll
  for (int s = 0; s < 8; s++) {
    float acc = 0.f;
#pragma unroll
    for (int q = 0; q < 4; q++) {
      float v = spv[q] + scp[s * cDH + q * 64 + l];
      v = fmaxf(v, 0.f);
      acc += v * w2v[q];
    }
#pragma unroll
    for (int o = 32; o > 0; o >>= 1) acc += __shfl_xor(acc, o);
    lg[s] = acc;
  }
  float m = lg[0];
#pragma unroll
  for (int s = 1; s < 8; s++) m = fmaxf(m, lg[s]);
  float sum = 0.f;
#pragma unroll
  for (int s = 0; s < 8; s++) sum += expf(lg[s] - m);
  if (l == 0) {
    int s0 = sid[b];
    wsel[b] = expf(lg[s0] - m) / sum;
  }
}

__global__ __launch_bounds__(256) void cvt_shared_k(const float* sf, bf16* ss) {
  int i = blockIdx.x * 256 + threadIdx.x;
  int r = i >> 7, c = (i & 127) * 4;
  f32x4 v = *(const f32x4*)(sf + (long)r * cD + c);
  short4v o;
#pragma unroll
  for (int j = 0; j < 4; j++) o[j] = __builtin_bit_cast(short, tob(v[j]));
  *(short4v*)(ss + (long)r * 1024 + c) = o;
}

// =====================  launcher  =====================
extern "C" void kernel_launch(void* const* d_in, const int* in_sizes, int n_in, void* d_out,
                              int out_size, void* d_ws, size_t ws_size, hipStream_t stream) {
  const void* x = d_in[0];
  const int* sid = (const int*)d_in[1];

  char* ws = (char*)d_ws;
  size_t off = 0;
  auto alloc = [&](size_t bytes) -> void* {
    void* p = ws + off;
    off += (bytes + 255) & ~(size_t)255;
    return p;
  };
  int* g_flag = (int*)alloc(64);
  float* g_gates = (float*)alloc((size_t)cB * 4 * 4);
  float* g_wsel = (float*)alloc((size_t)cB * 4);
  int* g_perm = (int*)alloc((size_t)cB * 4);
  int* g_bh = (int*)alloc(64 * cS * 4);
  int* g_base = (int*)alloc(64 * cS * 4);
  int* g_cum = (int*)alloc(64);
  float* g_scp = (float*)alloc((size_t)cS * cDH * 4);
  float* g_small = (float*)alloc((size_t)300000 * 4);
  bf16* g_xb = (bf16*)alloc((size_t)cB * cD * 2);
  bf16* w1t = (bf16*)alloc((size_t)cE * cH * cD * 2);
  bf16* w2cat = (bf16*)alloc((size_t)cD * 4096 * 2);
  bf16* s1t = (bf16*)alloc((size_t)cS * cH * cD * 2);
  bf16* s2t = (bf16*)alloc((size_t)cS * cD * cH * 2);
  bf16* a1t = (bf16*)alloc((size_t)cDH * cD * 2);
  bf16* owpair = (bf16*)alloc((size_t)1024 * 1024 * 2);
  bf16* g_ss = (bf16*)alloc((size_t)cB * 1024 * 2);
  size_t fixed_end = off;
  const size_t MB = 1024ull * 1024ull;
  const bool BIG = (ws_size == 0) || (fixed_end + 135 * MB <= ws_size);
  char* g_big = (char*)alloc(BIG ? 135 * MB : 68 * MB);
  (void)in_sizes;
  (void)n_in;
  (void)out_size;

  dim3 blk(256);
  probe_k<<<1, blk, 0, stream>>>(x, g_flag);
  cvtx_k<<<cB * cD / 8 / 256, blk, 0, stream>>>(x, g_xb, g_flag);

  const int O_GW = 0, O_GB = 2048, O_SB1 = 2052, O_SB2 = 6148, O_PB1 = 8196, O_PB2 = 16388,
            O_EMB = 20484, O_AW1 = 24580, O_AB1 = 286724, O_AW2 = 286980, O_OB = 287236,
            O_END = 287748;
  {
    CvtDesc d;
    const void* srcs[11] = {d_in[2],  d_in[3],  d_in[5],  d_in[7],  d_in[9], d_in[11],
                            d_in[12], d_in[13], d_in[14], d_in[15], d_in[18]};
    int offs[12] = {O_GW, O_GB, O_SB1, O_SB2, O_PB1, O_PB2, O_EMB, O_AW1, O_AB1, O_AW2, O_OB,
                    O_END};
    for (int i = 0; i < 11; i++) d.src[i] = srcs[i];
    for (int i = 0; i < 12; i++) d.off[i] = offs[i];
    cvt_smalls_k<<<(O_END + 255) / 256, blk, 0, stream>>>(d, g_flag, g_small);
  }

  transpose_k<<<dim3(cH / 32, cD / 32, cE), blk, 0, stream>>>(d_in[4], w1t, cH, cD, 0,
                                                              (long)cD * cH, (long)cH * cD, g_flag);
  transpose_k<<<dim3(cD / 32, cH / 32, cE), blk, 0, stream>>>(d_in[6], w2cat, cD, 4096, 0,
                                                              (long)cH * cD, 1024, g_flag);
  transpose_k<<<dim3(cH / 32, cD / 32, cS), blk, 0, stream>>>(d_in[8], s1t, cH, cD, 0,
                                                              (long)cD * cH, (long)cH * cD, g_flag);
  transpose_k<<<dim3(cD / 32, cH / 32, cS), blk, 0, stream>>>(d_in[10], s2t, cD, cH, 0,
                                                              (long)cH * cD, (long)cD * cH, g_flag);
  transpose_k<<<dim3(cDH / 32, cD / 32, 1), blk, 0, stream>>>(d_in[13], a1t, cDH, cD, 0, 0, 0,
                                                              g_flag);
  owt_k<<<dim3(cD / 32, cD / 32, 4), blk, 0, stream>>>(d_in[17], owpair, g_flag);

  gates_k<<<cB / 4, blk, 0, stream>>>(g_xb, g_small + O_GW, g_small + O_GB, g_gates);
  bhist_k<<<cB / 256, blk, 0, stream>>>(sid, g_bh);
  bbase_k<<<1, 64, 0, stream>>>(g_bh, g_base, g_cum);
  bscat_k<<<cB / 256, blk, 0, stream>>>(sid, g_base, g_perm);

  if (BIG) {
    bf16* h4 = (bf16*)g_big;     // [16384,4096]
    float* sp = (float*)g_big;   // [16384,256] (after h4 dead)
    bf16* hspec = (bf16*)g_big;  // [16384,1024] (after sp dead)
    {
      GArgs a{};
      a.A = g_xb; a.lda = cD; a.Bt = w1t; a.ldb = cD;
      a.C = h4; a.ldc = 4096; a.M = cB; a.N = 4096; a.K = cD;
      a.bias = g_small + O_SB1; a.gates = g_gates;
      gemm_k<6, false, false, false><<<dim3(32, cB / 128), blk, 0, stream>>>(a);
    }
    {
      // GEMM2 with BM=64: grid 4x256 = 1024 blocks -> 4 blocks/CU
      GArgs a{};
      a.A = h4; a.lda = 4096; a.Bt = w2cat; a.ldb = 4096;
      a.C = g_ss; a.ldc = 1024; a.M = cB; a.N = cD; a.K = 4096;
      a.bias = g_small + O_SB2; a.gates = g_gates;
      gemm_k<7, false, false, false, 64><<<dim3(cD / 128, cB / 64), blk, 0, stream>>>(a);
    }
    {
      // sp GEMM with BM=64: grid 2x256 = 512 blocks -> 2 blocks/CU
      GArgs a{};
      a.A = g_ss; a.lda = 1024; a.Bt = a1t; a.ldb = cD;
      a.C = sp; a.ldc = cDH; a.M = cB; a.N = cDH; a.K = cD;
      gemm_k<3, false, false, false, 64><<<dim3(cDH / 128, cB / 64), blk, 0, stream>>>(a);
    }
    scenpart_k<<<dim3(cS, 8), blk, 0, stream>>>(g_small + O_EMB, g_small + O_AW1, g_small + O_AB1,
                                                g_scp);
    wsel_k<<<cB / 4, blk, 0, stream>>>(sp, g_scp, g_small + O_AW2, sid, g_wsel);
    {
      GArgs a{};
      a.A = g_xb; a.lda = cD; a.Bt = s1t; a.ldb = cD; a.bt_stride = (long)cH * cD;
      a.C = hspec; a.ldc = cH; a.M = cB; a.N = cH; a.K = cD;
      a.bias = g_small + O_PB1; a.bias_stride = cH;
      a.perm = g_perm; a.cum = g_cum;
      gemm_k<1, true, true, false><<<dim3(cH / 128, cB / 128, cS), blk, 0, stream>>>(a);
    }
    {
      GArgs a{};
      a.A = hspec; a.lda = cH; a.Bt = s2t; a.ldb = cH; a.bt_stride = (long)cD * cH;
      a.C = g_ss + 512; a.ldc = 1024; a.M = cB; a.N = cD; a.K = cH;
      a.bias = g_small + O_PB2; a.bias_stride = cD;
      a.perm = g_perm; a.cum = g_cum;
      gemm_k<4, true, false, true><<<dim3(cD / 128, cB / 128, cS), blk, 0, stream>>>(a);
    }
    {
      // merged P1+out: B = owpair [1024 rows][K=1024]
      GArgs a{};
      a.A = g_ss; a.lda = 1024; a.Bt = owpair; a.ldb = 1024;
      a.C = d_out; a.ldc = cD; a.M = cB; a.N = 1024; a.K = 1024;
      a.bias = g_small + O_OB; a.wsel = g_wsel; a.dflag = g_flag;
      gemm_k<9, false, false, false><<<dim3(8, cB / 128), blk, 0, stream>>>(a);
    }
  } else {
    // fallback: sequential-expert structure inside 68MB scratch
    float* f32a = (float*)g_big;            // [16384,512] f32
    bf16* hbuf = (bf16*)(g_big + 34 * MB);  // [16384,1024] bf16
    for (int e = 0; e < cE; e++) {
      GArgs a1{};
      a1.A = g_xb; a1.lda = cD; a1.Bt = w1t + (size_t)e * cH * cD; a1.ldb = cD;
      a1.C = hbuf; a1.ldc = cH; a1.M = cB; a1.N = cH; a1.K = cD;
      a1.bias = g_small + O_SB1 + e * cH;
      gemm_k<1, false, false, false><<<dim3(cH / 128, cB / 128), blk, 0, stream>>>(a1);
      GArgs a2{};
      a2.A = hbuf; a2.lda = cH; a2.Bt = w2cat + (size_t)e * 1024; a2.ldb = 4096;
      a2.C = f32a; a2.ldc = cD; a2.M = cB; a2.N = cD; a2.K = cH;
      a2.bias = g_small + O_SB2 + e * cD; a2.gates = g_gates; a2.eidx = e;
      gemm_k<2, false, false, false><<<dim3(cD / 128, cB / 128), blk, 0, stream>>>(a2);
    }
    cvt_shared_k<<<cB * 128 / 256, blk, 0, stream>>>(f32a, g_ss);
    {
      GArgs a{};
      a.A = g_xb; a.lda = cD; a.Bt = s1t; a.ldb = cD; a.bt_stride = (long)cH * cD;
      a.C = hbuf; a.ldc = cH; a.M = cB; a.N = cH; a.K = cD;
      a.bias = g_small + O_PB1; a.bias_stride = cH;
      a.perm = g_perm; a.cum = g_cum;
      gemm_k<1, true, true, false><<<dim3(cH / 128, cB / 128, cS), blk, 0, stream>>>(a);
    }
    {
      GArgs a{};
      a.A = hbuf; a.lda = cH; a.Bt = s2t; a.ldb = cH; a.bt_stride = (long)cD * cH;
      a.C = g_ss + 512; a.ldc = 1024; a.M = cB; a.N = cD; a.K = cH;
      a.bias = g_small + O_PB2; a.bias_stride = cD;
      a.perm = g_perm; a.cum = g_cum;
      gemm_k<4, true, false, true><<<dim3(cD / 128, cB / 128, cS), blk, 0, stream>>>(a);
    }
    {
      GArgs a{};
      a.A = g_ss; a.lda = 1024; a.Bt = a1t; a.ldb = cD;
      a.C = f32a; a.ldc = cDH; a.M = cB; a.N = cDH; a.K = cD;
      gemm_k<3, false, false, false><<<dim3(cDH / 128, cB / 128), blk, 0, stream>>>(a);
    }
    scenpart_k<<<dim3(cS, 8), blk, 0, stream>>>(g_small + O_EMB, g_small + O_AW1, g_small + O_AB1,
                                                g_scp);
    wsel_k<<<cB / 4, blk, 0, stream>>>(f32a, g_scp, g_small + O_AW2, sid, g_wsel);
    {
      GArgs a{};
      a.A = g_ss; a.lda = 1024; a.Bt = owpair; a.ldb = 1024;
      a.C = d_out; a.ldc = cD; a.M = cB; a.N = 1024; a.K = 1024;
      a.bias = g_small + O_OB; a.wsel = g_wsel; a.dflag = g_flag;
      gemm_k<9, false, false, false><<<dim3(8, cB / 128), blk, 0, stream>>>(a);
    }
  }
}

// Round 9
// 419.142 us; speedup vs baseline: 1.0336x; 1.0336x over previous
//
#include <hip/hip_runtime.h>
#include <hip/hip_bf16.h>
#include <stdint.h>

typedef __hip_bfloat16 bf16;
typedef __attribute__((ext_vector_type(8))) short short8;
typedef __attribute__((ext_vector_type(4))) short short4v;
typedef __attribute__((ext_vector_type(4))) float f32x4;

constexpr int cB = 16384, cD = 512, cH = 1024, cS = 8, cE = 4, cDH = 256;

__device__ __forceinline__ float tof(bf16 v) { return __bfloat162float(v); }
__device__ __forceinline__ bf16 tob(float v) { return __float2bfloat16(v); }
__device__ __forceinline__ float b2f(short s) {
  uint32_t u = ((uint32_t)(uint16_t)s) << 16;
  return __builtin_bit_cast(float, u);
}
__device__ __forceinline__ float ldf(const void* p, long i, int isbf) {
  return isbf ? b2f(((const short*)p)[i]) : ((const float*)p)[i];
}
__device__ __forceinline__ void stbf_nt(bf16* p, float v) {
  __builtin_nontemporal_store(__builtin_bit_cast(short, tob(v)), (short*)p);
}

__device__ __forceinline__ void gload_lds16(const bf16* g, char* l) {
  __builtin_amdgcn_global_load_lds(
      (const __attribute__((address_space(1))) void*)g,
      (__attribute__((address_space(3))) void*)l, 16, 0, 0);
}

// ---- dtype probe ----
__global__ __launch_bounds__(256) void probe_k(const void* x, int* flag) {
  __shared__ int sh[256];
  const unsigned short* u = (const unsigned short*)x;
  int cnt = 0;
  for (int i = threadIdx.x; i < 2048; i += 256) {
    float v = fabsf(b2f((short)u[2 * i]));
    cnt += (v > 1e-5f && v < 1e3f) ? 1 : 0;
  }
  sh[threadIdx.x] = cnt;
  __syncthreads();
  for (int s = 128; s > 0; s >>= 1) {
    if (threadIdx.x < s) sh[threadIdx.x] += sh[threadIdx.x + s];
    __syncthreads();
  }
  if (threadIdx.x == 0) flag[0] = (sh[0] > 1024) ? 1 : 0;
}

__global__ __launch_bounds__(256) void cvtx_k(const void* x, bf16* xb, const int* flag) {
  int g = blockIdx.x * 256 + threadIdx.x;
  if (flag[0]) {
    ((short8*)xb)[g] = ((const short8*)x)[g];
  } else {
    const f32x4* xf = (const f32x4*)x;
    f32x4 v0 = xf[2 * g], v1 = xf[2 * g + 1];
    short8 o;
#pragma unroll
    for (int j = 0; j < 4; j++) {
      o[j] = __builtin_bit_cast(short, tob(v0[j]));
      o[j + 4] = __builtin_bit_cast(short, tob(v1[j]));
    }
    ((short8*)xb)[g] = o;
  }
}

struct CvtDesc {
  const void* src[11];
  int off[12];
};
__global__ __launch_bounds__(256) void cvt_smalls_k(CvtDesc d, const int* flag, float* dst) {
  int i = blockIdx.x * 256 + threadIdx.x;
  if (i >= d.off[11]) return;
  int isb = flag[0];
  int j = 0;
  while (i >= d.off[j + 1]) j++;
  dst[i] = ldf(d.src[j], i - d.off[j], isb);
}

__global__ __launch_bounds__(256) void transpose_k(const void* in, bf16* out, int ldin, int ldout,
                                                   long in_off, long in_bs, long out_bs,
                                                   const int* flag) {
  __shared__ float tile[32][33];
  int isb = flag[0];
  long src0 = in_off + (long)blockIdx.z * in_bs;
  bf16* dst = out + (long)blockIdx.z * out_bs;
  int c0 = blockIdx.x * 32, r0 = blockIdx.y * 32;
  int tx = threadIdx.x & 31, ty = threadIdx.x >> 5;
#pragma unroll
  for (int i = 0; i < 4; i++)
    tile[ty + i * 8][tx] = ldf(in, src0 + (long)(r0 + ty + i * 8) * ldin + c0 + tx, isb);
  __syncthreads();
#pragma unroll
  for (int i = 0; i < 4; i++)
    dst[(long)(c0 + ty + i * 8) * ldout + r0 + tx] = tob(tile[tx][ty + i * 8]);
}

// ---- out_w -> owpair: interleaved [W0;W2]^T / [W1;W3]^T rows (EPI9 pairing) ----
__global__ __launch_bounds__(256) void owt_k(const void* ow, bf16* owpair, const int* flag) {
  __shared__ float tile[32][33];
  int isb = flag[0];
  int z = blockIdx.z;
  int m = z & 1, kb = (z >> 1) * 512;
  long base = (long)z * 512 * cD;
  int c0 = blockIdx.x * 32, r0 = blockIdx.y * 32;
  int tx = threadIdx.x & 31, ty = threadIdx.x >> 5;
#pragma unroll
  for (int i = 0; i < 4; i++)
    tile[ty + i * 8][tx] = ldf(ow, base + (long)(r0 + ty + i * 8) * cD + c0 + tx, isb);
  __syncthreads();
#pragma unroll
  for (int i = 0; i < 4; i++) {
    int n = c0 + ty + i * 8;
    int R = ((n >> 6) << 7) + (((n >> 5) & 1) << 6) + (m << 5) + (((n >> 4) & 1) << 4) + (n & 15);
    owpair[(long)R * 1024 + kb + r0 + tx] = tob(tile[tx][ty + i * 8]);
  }
}

// ================  128x128 GEMM engine (BM=128; optional split-K via z)  ================
// EPI: 1 relu(acc+bias)->bf16 [nt] ; 2 C(f32) (=/+=) gates*(acc+bias)
//      3 C(f32)=acc ; 4 (acc+bias)->bf16 ; 6 gates[b,n>>10]*relu(acc+bias)->bf16 [nt]
//      7 acc + gates[b,:]·b2[:,n] -> bf16 ; 8 acc->bf16 (supports SPLITK col offset)
//      9 merged: acc1 + wsel*acc2 + bias -> out
struct GArgs {
  const bf16* A; int lda;
  const bf16* Bt; int ldb; long bt_stride;
  void* C; int ldc;
  int M, N, K;
  const float* bias; int bias_stride;
  const float* gates; int eidx;  // eidx doubles as SPLITK C-col offset
  const int* perm; const int* cum;
  const float* wsel;
  const int* dflag;
};

template <int EPI, bool GROUPED, bool GATHER_A, bool SCATTER_C, bool SPLITK = false>
__global__ __launch_bounds__(256, 4) void gemm_k(GArgs a) {
  __shared__ char smem[32768];
  char* ldsA = smem;
  char* ldsB = smem + 16384;

  int bxs, bys;
  if constexpr (!GROUPED) {
    // XCD-aware bijective remap (T1/m204); grouped kernels keep identity
    // (early-exit would concentrate live blocks on XCD0 — r4 post-mortem).
    const int gx = gridDim.x;
    const int nwg = gx * gridDim.y;
    const int d = blockIdx.y * gx + blockIdx.x;
    const int q = nwg >> 3, r = nwg & 7;
    const int xcd = d & 7, di = d >> 3;
    const int logical = (xcd < r ? xcd * (q + 1) : r * (q + 1) + (xcd - r) * q) + di;
    bxs = logical % gx;
    bys = logical / gx;
  } else {
    bxs = blockIdx.x;
    bys = blockIdx.y;
  }

  int g0, cnt;
  if constexpr (GROUPED) {
    int z = blockIdx.z;
    g0 = a.cum[z];
    cnt = a.cum[z + 1] - g0;
  } else {
    g0 = 0;
    cnt = a.M;
  }
  const int ptile = bys * 128;
  if (ptile >= cnt) return;
  const int n0 = bxs * 128;
  const int zk = SPLITK ? blockIdx.z * a.K : 0;   // K-offset of this split
  const int zc = SPLITK ? blockIdx.z * a.eidx : 0;  // C col offset of this split

  const int t = threadIdx.x, w = t >> 6, l = t & 63;
  const int wm = w >> 1, wn = w & 1;

  const bf16* bt = a.Bt + (GROUPED ? (long)blockIdx.z * a.bt_stride : 0);
  const float* bias = a.bias ? (a.bias + (GROUPED ? blockIdx.z * a.bias_stride : 0)) : nullptr;

  const bf16* aSrc[4];
  const bf16* bSrc[4];
  int ldsOff[4];
#pragma unroll
  for (int c = 0; c < 4; c++) {
    int pos = w * 4096 + c * 1024 + l * 16;
    int row = pos >> 7;
    int su = ((((pos >> 4) & 7) ^ (row & 7))) * 8;
    int p = ptile + row;
    if (p > cnt - 1) p = cnt - 1;
    int ar;
    if constexpr (GATHER_A) ar = a.perm[g0 + p];
    else ar = g0 + p;
    aSrc[c] = a.A + (long)ar * a.lda + zk + su;
    bSrc[c] = bt + (long)(n0 + row) * a.ldb + zk + su;
    ldsOff[c] = w * 4096 + c * 1024;
  }

  f32x4 zero = {0.f, 0.f, 0.f, 0.f};
  f32x4 acc[4][4];
#pragma unroll
  for (int i = 0; i < 4; i++)
#pragma unroll
    for (int j = 0; j < 4; j++) acc[i][j] = zero;

  const int nkt = a.K >> 6;
  for (int kt = 0; kt < nkt; ++kt) {
#pragma unroll
    for (int c = 0; c < 4; c++) gload_lds16(aSrc[c] + kt * 64, ldsA + ldsOff[c]);
#pragma unroll
    for (int c = 0; c < 4; c++) gload_lds16(bSrc[c] + kt * 64, ldsB + ldsOff[c]);
    __syncthreads();
#pragma unroll
    for (int kk = 0; kk < 2; kk++) {
      short8 af[4], bv[4];
#pragma unroll
      for (int mi = 0; mi < 4; mi++) {
        int row = wm * 64 + mi * 16 + (l & 15);
        int kg = kk * 4 + (l >> 4);
        int off = row * 128 + ((kg ^ (row & 7)) << 4);
        af[mi] = *(const short8*)(ldsA + off);
      }
#pragma unroll
      for (int ni = 0; ni < 4; ni++) {
        int row = wn * 64 + ni * 16 + (l & 15);
        int kg = kk * 4 + (l >> 4);
        int off = row * 128 + ((kg ^ (row & 7)) << 4);
        bv[ni] = *(const short8*)(ldsB + off);
      }
#pragma unroll
      for (int mi = 0; mi < 4; mi++)
#pragma unroll
        for (int ni = 0; ni < 4; ni++)
          acc[mi][ni] =
              __builtin_amdgcn_mfma_f32_16x16x32_bf16(af[mi], bv[ni], acc[mi][ni], 0, 0, 0);
    }
    __syncthreads();
  }

  const int l15 = l & 15, lg4 = l >> 4;
  int outbf = 1;
  if constexpr (EPI == 9) outbf = a.dflag[0];
#pragma unroll
  for (int mi = 0; mi < 4; mi++) {
#pragma unroll
    for (int j = 0; j < 4; j++) {
      int p = ptile + wm * 64 + mi * 16 + lg4 * 4 + j;
      if (p >= cnt) continue;
      int crow;
      if constexpr (SCATTER_C) crow = a.perm[g0 + p];
      else crow = g0 + p;
      if constexpr (EPI == 9) {
        float wv = a.wsel[crow];
#pragma unroll
        for (int ni = 0; ni < 2; ni++) {
          int n = (n0 >> 1) + wn * 32 + ni * 16 + l15;
          float o = acc[mi][ni][j] + wv * acc[mi][ni + 2][j] + a.bias[n];
          if (outbf) ((bf16*)a.C)[(long)crow * a.ldc + n] = tob(o);
          else ((float*)a.C)[(long)crow * a.ldc + n] = o;
        }
        continue;
      }
#pragma unroll
      for (int ni = 0; ni < 4; ni++) {
        int n = n0 + wn * 64 + ni * 16 + l15;
        float v = acc[mi][ni][j];
        if constexpr (EPI == 1) {
          v += bias[n];
          v = fmaxf(v, 0.f);
          stbf_nt(&((bf16*)a.C)[(long)crow * a.ldc + n], v);
        } else if constexpr (EPI == 2) {
          float g = a.gates[(long)(g0 + p) * 4 + a.eidx];
          v = g * (v + bias[n]);
          float* Cf = (float*)a.C;
          long idx = (long)crow * a.ldc + n;
          if (a.eidx == 0) Cf[idx] = v;
          else Cf[idx] += v;
        } else if constexpr (EPI == 3) {
          ((float*)a.C)[(long)crow * a.ldc + n] = v;
        } else if constexpr (EPI == 4) {
          v += bias[n];
          ((bf16*)a.C)[(long)crow * a.ldc + n] = tob(v);
        } else if constexpr (EPI == 6) {
          float g = a.gates[(long)(g0 + p) * 4 + (n >> 10)];
          v = g * fmaxf(v + bias[n], 0.f);
          stbf_nt(&((bf16*)a.C)[(long)crow * a.ldc + n], v);
        } else if constexpr (EPI == 7) {
          const float* gr = a.gates + (long)(g0 + p) * 4;
          v += gr[0] * bias[n] + gr[1] * bias[512 + n] + gr[2] * bias[1024 + n] +
               gr[3] * bias[1536 + n];
          ((bf16*)a.C)[(long)crow * a.ldc + n] = tob(v);
        } else if constexpr (EPI == 8) {
          ((bf16*)a.C)[(long)crow * a.ldc + n + zc] = tob(v);
        }
      }
    }
  }
}

// ---- split-K combine: ss[:, :512] = p0 + p1 + gates·b2 (p1 lives in ss[:,512:]) ----
__global__ __launch_bounds__(256) void combine_k(bf16* ss, const float* gates, const float* sb2) {
  long i = (long)blockIdx.x * 256 + threadIdx.x;  // one per 8 cols: B*64 total
  int r = (int)(i >> 6);
  int c8 = (int)(i & 63) * 8;
  short8 p0 = *(const short8*)(ss + (long)r * 1024 + c8);
  short8 p1 = *(const short8*)(ss + (long)r * 1024 + 512 + c8);
  const float* gr = gates + (long)r * 4;
  float g0 = gr[0], g1 = gr[1], g2 = gr[2], g3 = gr[3];
  short8 o;
#pragma unroll
  for (int j = 0; j < 8; j++) {
    int c = c8 + j;
    float v = b2f(p0[j]) + b2f(p1[j]) + g0 * sb2[c] + g1 * sb2[512 + c] + g2 * sb2[1024 + c] +
              g3 * sb2[1536 + c];
    o[j] = __builtin_bit_cast(short, tob(v));
  }
  *(short8*)(ss + (long)r * 1024 + c8) = o;
}

// =====================  small kernels  =====================
__global__ __launch_bounds__(256) void gates_k(const bf16* x, const float* gw, const float* gb,
                                               float* gates) {
  int b = blockIdx.x * 4 + (threadIdx.x >> 6);
  int l = threadIdx.x & 63;
  short8 xv = *(const short8*)(x + (long)b * cD + l * 8);
  float a0 = 0, a1 = 0, a2 = 0, a3 = 0;
#pragma unroll
  for (int j = 0; j < 8; j++) {
    float xf = b2f(xv[j]);
    f32x4 wr = *(const f32x4*)(gw + (l * 8 + j) * 4);
    a0 += xf * wr[0];
    a1 += xf * wr[1];
    a2 += xf * wr[2];
    a3 += xf * wr[3];
  }
#pragma unroll
  for (int o = 32; o > 0; o >>= 1) {
    a0 += __shfl_xor(a0, o);
    a1 += __shfl_xor(a1, o);
    a2 += __shfl_xor(a2, o);
    a3 += __shfl_xor(a3, o);
  }
  a0 += gb[0];
  a1 += gb[1];
  a2 += gb[2];
  a3 += gb[3];
  float m = fmaxf(fmaxf(a0, a1), fmaxf(a2, a3));
  float e0 = expf(a0 - m), e1 = expf(a1 - m), e2 = expf(a2 - m), e3 = expf(a3 - m);
  float s = e0 + e1 + e2 + e3;
  if (l == 0) {
    float* gp = gates + (long)b * 4;
    gp[0] = e0 / s;
    gp[1] = e1 / s;
    gp[2] = e2 / s;
    gp[3] = e3 / s;
  }
}

__global__ __launch_bounds__(256) void bhist_k(const int* sid, int* bh) {
  int blk = blockIdx.x, t = threadIdx.x;
  __shared__ int h[cS];
  if (t < cS) h[t] = 0;
  __syncthreads();
  int s = sid[blk * 256 + t];
#pragma unroll
  for (int q = 0; q < cS; q++) {
    unsigned long long m = __ballot(s == q);
    if ((t & 63) == 0) atomicAdd(&h[q], __popcll(m));
  }
  __syncthreads();
  if (t < cS) bh[blk * cS + t] = h[t];
}

__global__ void bbase_k(const int* bh, int* base, int* cum) {
  __shared__ int tot[cS];
  int s = threadIdx.x;
  if (s < cS) {
    int run = 0;
    for (int b = 0; b < 64; b++) {
      base[b * cS + s] = run;
      run += bh[b * cS + s];
    }
    tot[s] = run;
  }
  __syncthreads();
  if (s == 0) {
    int run = 0;
    for (int q = 0; q < cS; q++) {
      cum[q] = run;
      run += tot[q];
    }
    cum[cS] = run;
  }
  __syncthreads();
  if (s < cS) {
    int c = cum[s];
    for (int b = 0; b < 64; b++) base[b * cS + s] += c;
  }
}

__global__ __launch_bounds__(256) void bscat_k(const int* sid, const int* base, int* perm) {
  int blk = blockIdx.x, t = threadIdx.x, w = t >> 6, l = t & 63;
  __shared__ int wc[4][cS];
  __shared__ int wb[4][cS];
  int s = sid[blk * 256 + t];
  int rank = 0;
#pragma unroll
  for (int q = 0; q < cS; q++) {
    unsigned long long m = __ballot(s == q);
    if (l == 0) wc[w][q] = __popcll(m);
    if (s == q) rank = __popcll(m & ((1ull << l) - 1ull));
  }
  __syncthreads();
  if (t < cS) {
    int run = 0;
#pragma unroll
    for (int ww = 0; ww < 4; ww++) {
      wb[ww][t] = run;
      run += wc[ww][t];
    }
  }
  __syncthreads();
  perm[base[blk * cS + s] + wb[w][s] + rank] = blk * 256 + t;
}

__global__ __launch_bounds__(256) void scenpart_k(const float* emb, const float* w1,
                                                  const float* b1, float* scp) {
  __shared__ float red[8][32];
  int s = blockIdx.x;
  int nl = threadIdx.x & 31;
  int n = blockIdx.y * 32 + nl;
  int dg = threadIdx.x >> 5;
  float a = 0.f;
#pragma unroll 4
  for (int d = dg * 64; d < dg * 64 + 64; d++) a += emb[s * cD + d] * w1[(long)(cD + d) * cDH + n];
  red[dg][nl] = a;
  __syncthreads();
  if (dg == 0) {
    float t = b1[n];
#pragma unroll
    for (int g = 0; g < 8; g++) t += red[g][nl];
    scp[s * cDH + n] = t;
  }
}

__global__ __launch_bounds__(256) void wsel_k(const float* sp, const float* scp, const float* w2,
                                              const int* sid, float* wsel) {
  int b = blockIdx.x * 4 + (threadIdx.x >> 6);
  int l = threadIdx.x & 63;
  float spv[4], w2v[4];
#pragma unroll
  for (int q = 0; q < 4; q++) {
    spv[q] = sp[(long)b * cDH + q * 64 + l];
    w2v[q] = w2[q * 64 + l];
  }
  float lg[8];
#pragma unroll
  for (int s = 0; s < 8; s++) {
    float acc = 0.f;
#pragma unroll
    for (int q = 0; q < 4; q++) {
      float v = spv[q] + scp[s * cDH + q * 64 + l];
      v = fmaxf(v, 0.f);
      acc += v * w2v[q];
    }
#pragma unroll
    for (int o = 32; o > 0; o >>= 1) acc += __shfl_xor(acc, o);
    lg[s] = acc;
  }
  float m = lg[0];
#pragma unroll
  for (int s = 1; s < 8; s++) m = fmaxf(m, lg[s]);
  float sum = 0.f;
#pragma unroll
  for (int s = 0; s < 8; s++) sum += expf(lg[s] - m);
  if (l == 0) {
    int s0 = sid[b];
    wsel[b] = expf(lg[s0] - m) / sum;
  }
}

__global__ __launch_bounds__(256) void cvt_shared_k(const float* sf, bf16* ss) {
  int i = blockIdx.x * 256 + threadIdx.x;
  int r = i >> 7, c = (i & 127) * 4;
  f32x4 v = *(const f32x4*)(sf + (long)r * cD + c);
  short4v o;
#pragma unroll
  for (int j = 0; j < 4; j++) o[j] = __builtin_bit_cast(short, tob(v[j]));
  *(short4v*)(ss + (long)r * 1024 + c) = o;
}

// =====================  launcher  =====================
extern "C" void kernel_launch(void* const* d_in, const int* in_sizes, int n_in, void* d_out,
                              int out_size, void* d_ws, size_t ws_size, hipStream_t stream) {
  const void* x = d_in[0];
  const int* sid = (const int*)d_in[1];

  char* ws = (char*)d_ws;
  size_t off = 0;
  auto alloc = [&](size_t bytes) -> void* {
    void* p = ws + off;
    off += (bytes + 255) & ~(size_t)255;
    return p;
  };
  int* g_flag = (int*)alloc(64);
  float* g_gates = (float*)alloc((size_t)cB * 4 * 4);
  float* g_wsel = (float*)alloc((size_t)cB * 4);
  int* g_perm = (int*)alloc((size_t)cB * 4);
  int* g_bh = (int*)alloc(64 * cS * 4);
  int* g_base = (int*)alloc(64 * cS * 4);
  int* g_cum = (int*)alloc(64);
  float* g_scp = (float*)alloc((size_t)cS * cDH * 4);
  float* g_small = (float*)alloc((size_t)300000 * 4);
  bf16* g_xb = (bf16*)alloc((size_t)cB * cD * 2);
  bf16* w1t = (bf16*)alloc((size_t)cE * cH * cD * 2);
  bf16* w2cat = (bf16*)alloc((size_t)cD * 4096 * 2);
  bf16* s1t = (bf16*)alloc((size_t)cS * cH * cD * 2);
  bf16* s2t = (bf16*)alloc((size_t)cS * cD * cH * 2);
  bf16* a1t = (bf16*)alloc((size_t)cDH * cD * 2);
  bf16* owpair = (bf16*)alloc((size_t)1024 * 1024 * 2);
  bf16* g_ss = (bf16*)alloc((size_t)cB * 1024 * 2);
  size_t fixed_end = off;
  const size_t MB = 1024ull * 1024ull;
  const bool BIG = (ws_size == 0) || (fixed_end + 135 * MB <= ws_size);
  char* g_big = (char*)alloc(BIG ? 135 * MB : 68 * MB);
  (void)in_sizes;
  (void)n_in;
  (void)out_size;

  dim3 blk(256);
  probe_k<<<1, blk, 0, stream>>>(x, g_flag);
  cvtx_k<<<cB * cD / 8 / 256, blk, 0, stream>>>(x, g_xb, g_flag);

  const int O_GW = 0, O_GB = 2048, O_SB1 = 2052, O_SB2 = 6148, O_PB1 = 8196, O_PB2 = 16388,
            O_EMB = 20484, O_AW1 = 24580, O_AB1 = 286724, O_AW2 = 286980, O_OB = 287236,
            O_END = 287748;
  {
    CvtDesc d;
    const void* srcs[11] = {d_in[2],  d_in[3],  d_in[5],  d_in[7],  d_in[9], d_in[11],
                            d_in[12], d_in[13], d_in[14], d_in[15], d_in[18]};
    int offs[12] = {O_GW, O_GB, O_SB1, O_SB2, O_PB1, O_PB2, O_EMB, O_AW1, O_AB1, O_AW2, O_OB,
                    O_END};
    for (int i = 0; i < 11; i++) d.src[i] = srcs[i];
    for (int i = 0; i < 12; i++) d.off[i] = offs[i];
    cvt_smalls_k<<<(O_END + 255) / 256, blk, 0, stream>>>(d, g_flag, g_small);
  }

  transpose_k<<<dim3(cH / 32, cD / 32, cE), blk, 0, stream>>>(d_in[4], w1t, cH, cD, 0,
                                                              (long)cD * cH, (long)cH * cD, g_flag);
  transpose_k<<<dim3(cD / 32, cH / 32, cE), blk, 0, stream>>>(d_in[6], w2cat, cD, 4096, 0,
                                                              (long)cH * cD, 1024, g_flag);
  transpose_k<<<dim3(cH / 32, cD / 32, cS), blk, 0, stream>>>(d_in[8], s1t, cH, cD, 0,
                                                              (long)cD * cH, (long)cH * cD, g_flag);
  transpose_k<<<dim3(cD / 32, cH / 32, cS), blk, 0, stream>>>(d_in[10], s2t, cD, cH, 0,
                                                              (long)cH * cD, (long)cD * cH, g_flag);
  transpose_k<<<dim3(cDH / 32, cD / 32, 1), blk, 0, stream>>>(d_in[13], a1t, cDH, cD, 0, 0, 0,
                                                              g_flag);
  owt_k<<<dim3(cD / 32, cD / 32, 4), blk, 0, stream>>>(d_in[17], owpair, g_flag);

  gates_k<<<cB / 4, blk, 0, stream>>>(g_xb, g_small + O_GW, g_small + O_GB, g_gates);
  bhist_k<<<cB / 256, blk, 0, stream>>>(sid, g_bh);
  bbase_k<<<1, 64, 0, stream>>>(g_bh, g_base, g_cum);
  bscat_k<<<cB / 256, blk, 0, stream>>>(sid, g_base, g_perm);

  if (BIG) {
    bf16* h4 = (bf16*)g_big;     // [16384,4096]
    float* sp = (float*)g_big;   // [16384,256] (after h4 dead)
    bf16* hspec = (bf16*)g_big;  // [16384,1024] (after sp dead)
    {
      GArgs a{};
      a.A = g_xb; a.lda = cD; a.Bt = w1t; a.ldb = cD;
      a.C = h4; a.ldc = 4096; a.M = cB; a.N = 4096; a.K = cD;
      a.bias = g_small + O_SB1; a.gates = g_gates;
      gemm_k<6, false, false, false><<<dim3(32, cB / 128), blk, 0, stream>>>(a);
    }
    {
      // GEMM2 split-K=2: z in {0,1}, each half K=2048; raw bf16 partials into
      // ss cols [z*512, z*512+512). (cols 512+ are temporary; grouped2
      // overwrites them AFTER combine.)
      GArgs a{};
      a.A = h4; a.lda = 4096; a.Bt = w2cat; a.ldb = 4096;
      a.C = g_ss; a.ldc = 1024; a.M = cB; a.N = cD; a.K = 2048;
      a.eidx = 512;
      gemm_k<8, false, false, false, true><<<dim3(cD / 128, cB / 128, 2), blk, 0, stream>>>(a);
    }
    combine_k<<<cB * 64 / 256, blk, 0, stream>>>(g_ss, g_gates, g_small + O_SB2);
    {
      GArgs a{};
      a.A = g_ss; a.lda = 1024; a.Bt = a1t; a.ldb = cD;
      a.C = sp; a.ldc = cDH; a.M = cB; a.N = cDH; a.K = cD;
      gemm_k<3, false, false, false><<<dim3(cDH / 128, cB / 128), blk, 0, stream>>>(a);
    }
    scenpart_k<<<dim3(cS, 8), blk, 0, stream>>>(g_small + O_EMB, g_small + O_AW1, g_small + O_AB1,
                                                g_scp);
    wsel_k<<<cB / 4, blk, 0, stream>>>(sp, g_scp, g_small + O_AW2, sid, g_wsel);
    {
      GArgs a{};
      a.A = g_xb; a.lda = cD; a.Bt = s1t; a.ldb = cD; a.bt_stride = (long)cH * cD;
      a.C = hspec; a.ldc = cH; a.M = cB; a.N = cH; a.K = cD;
      a.bias = g_small + O_PB1; a.bias_stride = cH;
      a.perm = g_perm; a.cum = g_cum;
      gemm_k<1, true, true, false><<<dim3(cH / 128, cB / 128, cS), blk, 0, stream>>>(a);
    }
    {
      GArgs a{};
      a.A = hspec; a.lda = cH; a.Bt = s2t; a.ldb = cH; a.bt_stride = (long)cD * cH;
      a.C = g_ss + 512; a.ldc = 1024; a.M = cB; a.N = cD; a.K = cH;
      a.bias = g_small + O_PB2; a.bias_stride = cD;
      a.perm = g_perm; a.cum = g_cum;
      gemm_k<4, true, false, true><<<dim3(cD / 128, cB / 128, cS), blk, 0, stream>>>(a);
    }
    {
      // merged P1+out: B = owpair [1024 rows][K=1024]
      GArgs a{};
      a.A = g_ss; a.lda = 1024; a.Bt = owpair; a.ldb = 1024;
      a.C = d_out; a.ldc = cD; a.M = cB; a.N = 1024; a.K = 1024;
      a.bias = g_small + O_OB; a.wsel = g_wsel; a.dflag = g_flag;
      gemm_k<9, false, false, false><<<dim3(8, cB / 128), blk, 0, stream>>>(a);
    }
  } else {
    // fallback: sequential-expert structure inside 68MB scratch
    float* f32a = (float*)g_big;            // [16384,512] f32
    bf16* hbuf = (bf16*)(g_big + 34 * MB);  // [16384,1024] bf16
    for (int e = 0; e < cE; e++) {
      GArgs a1{};
      a1.A = g_xb; a1.lda = cD; a1.Bt = w1t + (size_t)e * cH * cD; a1.ldb = cD;
      a1.C = hbuf; a1.ldc = cH; a1.M = cB; a1.N = cH; a1.K = cD;
      a1.bias = g_small + O_SB1 + e * cH;
      gemm_k<1, false, false, false><<<dim3(cH / 128, cB / 128), blk, 0, stream>>>(a1);
      GArgs a2{};
      a2.A = hbuf; a2.lda = cH; a2.Bt = w2cat + (size_t)e * 1024; a2.ldb = 4096;
      a2.C = f32a; a2.ldc = cD; a2.M = cB; a2.N = cD; a2.K = cH;
      a2.bias = g_small + O_SB2 + e * cD; a2.gates = g_gates; a2.eidx = e;
      gemm_k<2, false, false, false><<<dim3(cD / 128, cB / 128), blk, 0, stream>>>(a2);
    }
    cvt_shared_k<<<cB * 128 / 256, blk, 0, stream>>>(f32a, g_ss);
    {
      GArgs a{};
      a.A = g_xb; a.lda = cD; a.Bt = s1t; a.ldb = cD; a.bt_stride = (long)cH * cD;
      a.C = hbuf; a.ldc = cH; a.M = cB; a.N = cH; a.K = cD;
      a.bias = g_small + O_PB1; a.bias_stride = cH;
      a.perm = g_perm; a.cum = g_cum;
      gemm_k<1, true, true, false><<<dim3(cH / 128, cB / 128, cS), blk, 0, stream>>>(a);
    }
    {
      GArgs a{};
      a.A = hbuf; a.lda = cH; a.Bt = s2t; a.ldb = cH; a.bt_stride = (long)cD * cH;
      a.C = g_ss + 512; a.ldc = 1024; a.M = cB; a.N = cD; a.K = cH;
      a.bias = g_small + O_PB2; a.bias_stride = cD;
      a.perm = g_perm; a.cum = g_cum;
      gemm_k<4, true, false, true><<<dim3(cD / 128, cB / 128, cS), blk, 0, stream>>>(a);
    }
    {
      GArgs a{};
      a.A = g_ss; a.lda = 1024; a.Bt = a1t; a.ldb = cD;
      a.C = f32a; a.ldc = cDH; a.M = cB; a.N = cDH; a.K = cD;
      gemm_k<3, false, false, false><<<dim3(cDH / 128, cB / 128), blk, 0, stream>>>(a);
    }
    scenpart_k<<<dim3(cS, 8), blk, 0, stream>>>(g_small + O_EMB, g_small + O_AW1, g_small + O_AB1,
                                                g_scp);
    wsel_k<<<cB / 4, blk, 0, stream>>>(f32a, g_scp, g_small + O_AW2, sid, g_wsel);
    {
      GArgs a{};
      a.A = g_ss; a.lda = 1024; a.Bt = owpair; a.ldb = 1024;
      a.C = d_out; a.ldc = cD; a.M = cB; a.N = 1024; a.K = 1024;
      a.bias = g_small + O_OB; a.wsel = g_wsel; a.dflag = g_flag;
      gemm_k<9, false, false, false><<<dim3(8, cB / 128), blk, 0, stream>>>(a);
    }
  }
}

// Round 10
// 405.902 us; speedup vs baseline: 1.0673x; 1.0326x over previous
//
#include <hip/hip_runtime.h>
#include <hip/hip_bf16.h>
#include <stdint.h>

typedef __hip_bfloat16 bf16;
typedef __attribute__((ext_vector_type(8))) short short8;
typedef __attribute__((ext_vector_type(4))) short short4v;
typedef __attribute__((ext_vector_type(4))) float f32x4;

constexpr int cB = 16384, cD = 512, cH = 1024, cS = 8, cE = 4, cDH = 256;

__device__ __forceinline__ float tof(bf16 v) { return __bfloat162float(v); }
__device__ __forceinline__ bf16 tob(float v) { return __float2bfloat16(v); }
__device__ __forceinline__ float b2f(short s) {
  uint32_t u = ((uint32_t)(uint16_t)s) << 16;
  return __builtin_bit_cast(float, u);
}
__device__ __forceinline__ float ldf(const void* p, long i, int isbf) {
  return isbf ? b2f(((const short*)p)[i]) : ((const float*)p)[i];
}
__device__ __forceinline__ void stbf_nt(bf16* p, float v) {
  __builtin_nontemporal_store(__builtin_bit_cast(short, tob(v)), (short*)p);
}

__device__ __forceinline__ void gload_lds16(const bf16* g, char* l) {
  __builtin_amdgcn_global_load_lds(
      (const __attribute__((address_space(1))) void*)g,
      (__attribute__((address_space(3))) void*)l, 16, 0, 0);
}

// ---- dtype probe ----
__global__ __launch_bounds__(256) void probe_k(const void* x, int* flag) {
  __shared__ int sh[256];
  const unsigned short* u = (const unsigned short*)x;
  int cnt = 0;
  for (int i = threadIdx.x; i < 2048; i += 256) {
    float v = fabsf(b2f((short)u[2 * i]));
    cnt += (v > 1e-5f && v < 1e3f) ? 1 : 0;
  }
  sh[threadIdx.x] = cnt;
  __syncthreads();
  for (int s = 128; s > 0; s >>= 1) {
    if (threadIdx.x < s) sh[threadIdx.x] += sh[threadIdx.x + s];
    __syncthreads();
  }
  if (threadIdx.x == 0) flag[0] = (sh[0] > 1024) ? 1 : 0;
}

__global__ __launch_bounds__(256) void cvtx_k(const void* x, bf16* xb, const int* flag) {
  int g = blockIdx.x * 256 + threadIdx.x;
  if (flag[0]) {
    ((short8*)xb)[g] = ((const short8*)x)[g];
  } else {
    const f32x4* xf = (const f32x4*)x;
    f32x4 v0 = xf[2 * g], v1 = xf[2 * g + 1];
    short8 o;
#pragma unroll
    for (int j = 0; j < 4; j++) {
      o[j] = __builtin_bit_cast(short, tob(v0[j]));
      o[j + 4] = __builtin_bit_cast(short, tob(v1[j]));
    }
    ((short8*)xb)[g] = o;
  }
}

struct CvtDesc {
  const void* src[11];
  int off[12];
};
__global__ __launch_bounds__(256) void cvt_smalls_k(CvtDesc d, const int* flag, float* dst) {
  int i = blockIdx.x * 256 + threadIdx.x;
  if (i >= d.off[11]) return;
  int isb = flag[0];
  int j = 0;
  while (i >= d.off[j + 1]) j++;
  dst[i] = ldf(d.src[j], i - d.off[j], isb);
}

__global__ __launch_bounds__(256) void transpose_k(const void* in, bf16* out, int ldin, int ldout,
                                                   long in_off, long in_bs, long out_bs,
                                                   const int* flag) {
  __shared__ float tile[32][33];
  int isb = flag[0];
  long src0 = in_off + (long)blockIdx.z * in_bs;
  bf16* dst = out + (long)blockIdx.z * out_bs;
  int c0 = blockIdx.x * 32, r0 = blockIdx.y * 32;
  int tx = threadIdx.x & 31, ty = threadIdx.x >> 5;
#pragma unroll
  for (int i = 0; i < 4; i++)
    tile[ty + i * 8][tx] = ldf(in, src0 + (long)(r0 + ty + i * 8) * ldin + c0 + tx, isb);
  __syncthreads();
#pragma unroll
  for (int i = 0; i < 4; i++)
    dst[(long)(c0 + ty + i * 8) * ldout + r0 + tx] = tob(tile[tx][ty + i * 8]);
}

// ---- out_w -> owpair: interleaved [W0;W2]^T / [W1;W3]^T rows (EPI9 pairing) ----
__global__ __launch_bounds__(256) void owt_k(const void* ow, bf16* owpair, const int* flag) {
  __shared__ float tile[32][33];
  int isb = flag[0];
  int z = blockIdx.z;
  int m = z & 1, kb = (z >> 1) * 512;
  long base = (long)z * 512 * cD;
  int c0 = blockIdx.x * 32, r0 = blockIdx.y * 32;
  int tx = threadIdx.x & 31, ty = threadIdx.x >> 5;
#pragma unroll
  for (int i = 0; i < 4; i++)
    tile[ty + i * 8][tx] = ldf(ow, base + (long)(r0 + ty + i * 8) * cD + c0 + tx, isb);
  __syncthreads();
#pragma unroll
  for (int i = 0; i < 4; i++) {
    int n = c0 + ty + i * 8;
    int R = ((n >> 6) << 7) + (((n >> 5) & 1) << 6) + (m << 5) + (((n >> 4) & 1) << 4) + (n & 15);
    owpair[(long)R * 1024 + kb + r0 + tx] = tob(tile[tx][ty + i * 8]);
  }
}

// ================  legacy 128x128 GEMM engine  ================
struct GArgs {
  const bf16* A; int lda;
  const bf16* Bt; int ldb; long bt_stride;
  void* C; int ldc;
  int M, N, K;
  const float* bias; int bias_stride;
  const float* gates; int eidx;  // eidx doubles as SPLITK C-col offset
  const int* perm; const int* cum;
  const float* wsel;
  const int* dflag;
};

template <int EPI, bool GROUPED, bool GATHER_A, bool SCATTER_C, bool SPLITK = false>
__global__ __launch_bounds__(256, 4) void gemm_k(GArgs a) {
  __shared__ char smem[32768];
  char* ldsA = smem;
  char* ldsB = smem + 16384;

  int bxs, bys;
  if constexpr (!GROUPED) {
    const int gx = gridDim.x;
    const int nwg = gx * gridDim.y;
    const int d = blockIdx.y * gx + blockIdx.x;
    const int q = nwg >> 3, r = nwg & 7;
    const int xcd = d & 7, di = d >> 3;
    const int logical = (xcd < r ? xcd * (q + 1) : r * (q + 1) + (xcd - r) * q) + di;
    bxs = logical % gx;
    bys = logical / gx;
  } else {
    bxs = blockIdx.x;
    bys = blockIdx.y;
  }

  int g0, cnt;
  if constexpr (GROUPED) {
    int z = blockIdx.z;
    g0 = a.cum[z];
    cnt = a.cum[z + 1] - g0;
  } else {
    g0 = 0;
    cnt = a.M;
  }
  const int ptile = bys * 128;
  if (ptile >= cnt) return;
  const int n0 = bxs * 128;
  const int zk = SPLITK ? blockIdx.z * a.K : 0;
  const int zc = SPLITK ? blockIdx.z * a.eidx : 0;

  const int t = threadIdx.x, w = t >> 6, l = t & 63;
  const int wm = w >> 1, wn = w & 1;

  const bf16* bt = a.Bt + (GROUPED ? (long)blockIdx.z * a.bt_stride : 0);
  const float* bias = a.bias ? (a.bias + (GROUPED ? blockIdx.z * a.bias_stride : 0)) : nullptr;

  const bf16* aSrc[4];
  const bf16* bSrc[4];
  int ldsOff[4];
#pragma unroll
  for (int c = 0; c < 4; c++) {
    int pos = w * 4096 + c * 1024 + l * 16;
    int row = pos >> 7;
    int su = ((((pos >> 4) & 7) ^ (row & 7))) * 8;
    int p = ptile + row;
    if (p > cnt - 1) p = cnt - 1;
    int ar;
    if constexpr (GATHER_A) ar = a.perm[g0 + p];
    else ar = g0 + p;
    aSrc[c] = a.A + (long)ar * a.lda + zk + su;
    bSrc[c] = bt + (long)(n0 + row) * a.ldb + zk + su;
    ldsOff[c] = w * 4096 + c * 1024;
  }

  f32x4 zero = {0.f, 0.f, 0.f, 0.f};
  f32x4 acc[4][4];
#pragma unroll
  for (int i = 0; i < 4; i++)
#pragma unroll
    for (int j = 0; j < 4; j++) acc[i][j] = zero;

  const int nkt = a.K >> 6;
  for (int kt = 0; kt < nkt; ++kt) {
#pragma unroll
    for (int c = 0; c < 4; c++) gload_lds16(aSrc[c] + kt * 64, ldsA + ldsOff[c]);
#pragma unroll
    for (int c = 0; c < 4; c++) gload_lds16(bSrc[c] + kt * 64, ldsB + ldsOff[c]);
    __syncthreads();
#pragma unroll
    for (int kk = 0; kk < 2; kk++) {
      short8 af[4], bv[4];
#pragma unroll
      for (int mi = 0; mi < 4; mi++) {
        int row = wm * 64 + mi * 16 + (l & 15);
        int kg = kk * 4 + (l >> 4);
        int off = row * 128 + ((kg ^ (row & 7)) << 4);
        af[mi] = *(const short8*)(ldsA + off);
      }
#pragma unroll
      for (int ni = 0; ni < 4; ni++) {
        int row = wn * 64 + ni * 16 + (l & 15);
        int kg = kk * 4 + (l >> 4);
        int off = row * 128 + ((kg ^ (row & 7)) << 4);
        bv[ni] = *(const short8*)(ldsB + off);
      }
#pragma unroll
      for (int mi = 0; mi < 4; mi++)
#pragma unroll
        for (int ni = 0; ni < 4; ni++)
          acc[mi][ni] =
              __builtin_amdgcn_mfma_f32_16x16x32_bf16(af[mi], bv[ni], acc[mi][ni], 0, 0, 0);
    }
    __syncthreads();
  }

  const int l15 = l & 15, lg4 = l >> 4;
  int outbf = 1;
  if constexpr (EPI == 9) outbf = a.dflag[0];
#pragma unroll
  for (int mi = 0; mi < 4; mi++) {
#pragma unroll
    for (int j = 0; j < 4; j++) {
      int p = ptile + wm * 64 + mi * 16 + lg4 * 4 + j;
      if (p >= cnt) continue;
      int crow;
      if constexpr (SCATTER_C) crow = a.perm[g0 + p];
      else crow = g0 + p;
      if constexpr (EPI == 9) {
        float wv = a.wsel[crow];
#pragma unroll
        for (int ni = 0; ni < 2; ni++) {
          int n = (n0 >> 1) + wn * 32 + ni * 16 + l15;
          float o = acc[mi][ni][j] + wv * acc[mi][ni + 2][j] + a.bias[n];
          if (outbf) ((bf16*)a.C)[(long)crow * a.ldc + n] = tob(o);
          else ((float*)a.C)[(long)crow * a.ldc + n] = o;
        }
        continue;
      }
#pragma unroll
      for (int ni = 0; ni < 4; ni++) {
        int n = n0 + wn * 64 + ni * 16 + l15;
        float v = acc[mi][ni][j];
        if constexpr (EPI == 1) {
          v += bias[n];
          v = fmaxf(v, 0.f);
          stbf_nt(&((bf16*)a.C)[(long)crow * a.ldc + n], v);
        } else if constexpr (EPI == 2) {
          float g = a.gates[(long)(g0 + p) * 4 + a.eidx];
          v = g * (v + bias[n]);
          float* Cf = (float*)a.C;
          long idx = (long)crow * a.ldc + n;
          if (a.eidx == 0) Cf[idx] = v;
          else Cf[idx] += v;
        } else if constexpr (EPI == 3) {
          ((float*)a.C)[(long)crow * a.ldc + n] = v;
        } else if constexpr (EPI == 4) {
          v += bias[n];
          ((bf16*)a.C)[(long)crow * a.ldc + n] = tob(v);
        } else if constexpr (EPI == 6) {
          float g = a.gates[(long)(g0 + p) * 4 + (n >> 10)];
          v = g * fmaxf(v + bias[n], 0.f);
          stbf_nt(&((bf16*)a.C)[(long)crow * a.ldc + n], v);
        } else if constexpr (EPI == 7) {
          const float* gr = a.gates + (long)(g0 + p) * 4;
          v += gr[0] * bias[n] + gr[1] * bias[512 + n] + gr[2] * bias[1024 + n] +
               gr[3] * bias[1536 + n];
          ((bf16*)a.C)[(long)crow * a.ldc + n] = tob(v);
        } else if constexpr (EPI == 8) {
          ((bf16*)a.C)[(long)crow * a.ldc + n + zc] = tob(v);
        }
      }
    }
  }
}

// ============  256x256 phase-interleaved engine (T2+T3+T4+T5, faithful)  ============
// 8 waves (2M x 4N), BK=64, per-wave out 128x64. LDS 2 bufs x 64KB
// {A[256][64] @0, B[256][64] @32KB}, XOR-swizzled 16B units (pre-swizzled
// global source, linear dest, XOR on read — rule #21).
// Per K-tile: 4 phases, each {ds_reads | stage freed regions ; barrier ;
// lgkmcnt(0) ; setprio(1) 16 MFMA setprio(0) ; barrier}.
// Region-free schedule: P1 reads A-lo+B-lo-stripes; P2 reads B-hi-stripes,
// stages Aq0,Aq2 (freed P1); P3 reads A-hi, stages Bq0-3 (freed P2);
// P4 stages Aq1,Aq3 (freed P3). 8 staging issues/wave/K-tile for tile t+2
// into buf[t&1]. Group top: vmcnt(8) (oldest 8 = tile t's stages) + barrier;
// vmcnt(0) only at last group.
struct G6Args {
  const bf16* A; int lda;
  const bf16* Bt; int ldb;
  void* C; int ldc;
  int N, K;
  const float* bias;
  const float* gates;
  const float* wsel;
  const int* dflag;
};

template <int EPI>
__global__ __launch_bounds__(512, 1) void g256_k(G6Args a) {
  extern __shared__ char sm[];
  const int t = threadIdx.x, w = t >> 6, l = t & 63;
  const int wm = w >> 2, wn = w & 3;

  const int gx = gridDim.x, nwg = gx * gridDim.y;
  const int dd = blockIdx.y * gx + blockIdx.x;
  const int q = nwg >> 3, r = nwg & 7;
  const int xcd = dd & 7, di = dd >> 3;
  const int logical = (xcd < r ? xcd * (q + 1) : r * (q + 1) + (xcd - r) * q) + di;
  const int m0 = (logical / gx) * 256, n0 = (logical % gx) * 256;
  const long zk = (long)blockIdx.z * a.K;  // split-K offset (z=0 when gridDim.z==1)

  // 8 staging descriptors: c 0-3 = A quarters (8KB each), 4-7 = B quarters.
  const bf16* srcP[8];
  int ldsO[8];
#pragma unroll
  for (int c = 0; c < 8; c++) {
    int pos = (c & 3) * 8192 + t * 16;
    int row = pos >> 7;
    int su = (((pos >> 4) & 7) ^ (row & 7)) * 8;
    if (c < 4) {
      srcP[c] = a.A + (long)(m0 + row) * a.lda + zk + su;
      ldsO[c] = (c & 3) * 8192 + w * 1024;
    } else {
      srcP[c] = a.Bt + (long)(n0 + row) * a.ldb + zk + su;
      ldsO[c] = 32768 + (c & 3) * 8192 + w * 1024;
    }
  }

  auto rdA = [&](char* buf, int mi, int kk) -> short8 {
    int row = wm * 128 + mi * 16 + (l & 15);
    int kg = kk * 4 + (l >> 4);
    return *(const short8*)(buf + row * 128 + ((kg ^ (row & 7)) << 4));
  };
  auto rdB = [&](char* buf, int ni, int kk) -> short8 {
    int row = wn * 64 + ni * 16 + (l & 15);
    int kg = kk * 4 + (l >> 4);
    return *(const short8*)(buf + 32768 + row * 128 + ((kg ^ (row & 7)) << 4));
  };

  f32x4 acc[8][4];
#pragma unroll
  for (int i = 0; i < 8; i++)
#pragma unroll
    for (int j = 0; j < 4; j++) acc[i][j] = {0.f, 0.f, 0.f, 0.f};

  const int nkt = a.K >> 6;
  // prologue: tile 0 -> buf0, tile 1 -> buf1
#pragma unroll
  for (int c = 0; c < 8; c++) gload_lds16(srcP[c], sm + ldsO[c]);
#pragma unroll
  for (int c = 0; c < 8; c++) gload_lds16(srcP[c] + 64, sm + 65536 + ldsO[c]);

  for (int kt = 0; kt < nkt; ++kt) {
    char* buf = sm + (kt & 1) * 65536;
    if (kt + 1 < nkt) asm volatile("s_waitcnt vmcnt(8)" ::: "memory");
    else asm volatile("s_waitcnt vmcnt(0)" ::: "memory");
    __builtin_amdgcn_s_barrier();

    const bool st = (kt + 2 < nkt);
    const int ko = (kt + 2) * 64;
    short8 fa[4][2], fb0[2][2], fb1[2][2];

    // ---- P1: read A-lo (8) + B ni0-1 (4); MFMA (mi0-3 x ni0-1)
#pragma unroll
    for (int mi = 0; mi < 4; mi++)
#pragma unroll
      for (int kk = 0; kk < 2; kk++) fa[mi][kk] = rdA(buf, mi, kk);
#pragma unroll
    for (int ni = 0; ni < 2; ni++)
#pragma unroll
      for (int kk = 0; kk < 2; kk++) fb0[ni][kk] = rdB(buf, ni, kk);
    __builtin_amdgcn_s_barrier();
    asm volatile("s_waitcnt lgkmcnt(0)" ::: "memory");
    __builtin_amdgcn_s_setprio(1);
#pragma unroll
    for (int mi = 0; mi < 4; mi++)
#pragma unroll
      for (int ni = 0; ni < 2; ni++)
#pragma unroll
        for (int kk = 0; kk < 2; kk++)
          acc[mi][ni] =
              __builtin_amdgcn_mfma_f32_16x16x32_bf16(fa[mi][kk], fb0[ni][kk], acc[mi][ni], 0, 0, 0);
    __builtin_amdgcn_s_setprio(0);
    __builtin_amdgcn_s_barrier();

    // ---- P2: read B ni2-3 (4); stage Aq0,Aq2; MFMA (mi0-3 x ni2-3)
#pragma unroll
    for (int ni = 0; ni < 2; ni++)
#pragma unroll
      for (int kk = 0; kk < 2; kk++) fb1[ni][kk] = rdB(buf, ni + 2, kk);
    if (st) {
      gload_lds16(srcP[0] + ko, buf + ldsO[0]);
      gload_lds16(srcP[2] + ko, buf + ldsO[2]);
    }
    __builtin_amdgcn_s_barrier();
    asm volatile("s_waitcnt lgkmcnt(0)" ::: "memory");
    __builtin_amdgcn_s_setprio(1);
#pragma unroll
    for (int mi = 0; mi < 4; mi++)
#pragma unroll
      for (int ni = 0; ni < 2; ni++)
#pragma unroll
        for (int kk = 0; kk < 2; kk++)
          acc[mi][ni + 2] = __builtin_amdgcn_mfma_f32_16x16x32_bf16(fa[mi][kk], fb1[ni][kk],
                                                                    acc[mi][ni + 2], 0, 0, 0);
    __builtin_amdgcn_s_setprio(0);
    __builtin_amdgcn_s_barrier();

    // ---- P3: read A-hi (8); stage Bq0-3; MFMA (mi4-7 x ni0-1)
#pragma unroll
    for (int mi = 0; mi < 4; mi++)
#pragma unroll
      for (int kk = 0; kk < 2; kk++) fa[mi][kk] = rdA(buf, mi + 4, kk);
    if (st) {
      gload_lds16(srcP[4] + ko, buf + ldsO[4]);
      gload_lds16(srcP[5] + ko, buf + ldsO[5]);
      gload_lds16(srcP[6] + ko, buf + ldsO[6]);
      gload_lds16(srcP[7] + ko, buf + ldsO[7]);
    }
    __builtin_amdgcn_s_barrier();
    asm volatile("s_waitcnt lgkmcnt(0)" ::: "memory");
    __builtin_amdgcn_s_setprio(1);
#pragma unroll
    for (int mi = 0; mi < 4; mi++)
#pragma unroll
      for (int ni = 0; ni < 2; ni++)
#pragma unroll
        for (int kk = 0; kk < 2; kk++)
          acc[mi + 4][ni] = __builtin_amdgcn_mfma_f32_16x16x32_bf16(fa[mi][kk], fb0[ni][kk],
                                                                    acc[mi + 4][ni], 0, 0, 0);
    __builtin_amdgcn_s_setprio(0);
    __builtin_amdgcn_s_barrier();

    // ---- P4: stage Aq1,Aq3; MFMA (mi4-7 x ni2-3)
    if (st) {
      gload_lds16(srcP[1] + ko, buf + ldsO[1]);
      gload_lds16(srcP[3] + ko, buf + ldsO[3]);
    }
    __builtin_amdgcn_s_barrier();
    __builtin_amdgcn_s_setprio(1);
#pragma unroll
    for (int mi = 0; mi < 4; mi++)
#pragma unroll
      for (int ni = 0; ni < 2; ni++)
#pragma unroll
        for (int kk = 0; kk < 2; kk++)
          acc[mi + 4][ni + 2] = __builtin_amdgcn_mfma_f32_16x16x32_bf16(
              fa[mi][kk], fb1[ni][kk], acc[mi + 4][ni + 2], 0, 0, 0);
    __builtin_amdgcn_s_setprio(0);
    __builtin_amdgcn_s_barrier();
  }

  // epilogue: C/D layout col=lane&15, row=(lane>>4)*4+reg (m89-verified)
  const int l15 = l & 15, lg4 = l >> 4;
  int outbf = 1;
  if constexpr (EPI == 9) outbf = a.dflag[0];
#pragma unroll
  for (int mi = 0; mi < 8; mi++) {
#pragma unroll
    for (int j = 0; j < 4; j++) {
      int crow = m0 + wm * 128 + mi * 16 + lg4 * 4 + j;
      if constexpr (EPI == 9) {
        float wv = a.wsel[crow];
#pragma unroll
        for (int ni = 0; ni < 2; ni++) {
          int R = n0 + wn * 64 + ni * 16 + l15;
          int n = ((R >> 7) << 6) | (((R >> 6) & 1) << 5) | (((R >> 4) & 1) << 4) | (R & 15);
          float o = acc[mi][ni][j] + wv * acc[mi][ni + 2][j] + a.bias[n];
          if (outbf) ((bf16*)a.C)[(long)crow * a.ldc + n] = tob(o);
          else ((float*)a.C)[(long)crow * a.ldc + n] = o;
        }
      } else {
#pragma unroll
        for (int ni = 0; ni < 4; ni++) {
          int n = n0 + wn * 64 + ni * 16 + l15;
          float v = acc[mi][ni][j];
          if constexpr (EPI == 6) {
            float g = a.gates[(long)crow * 4 + (n >> 10)];
            v = g * fmaxf(v + a.bias[n], 0.f);
            stbf_nt(&((bf16*)a.C)[(long)crow * a.ldc + n], v);
          } else if constexpr (EPI == 8) {
            ((bf16*)a.C)[(long)crow * a.ldc + n + blockIdx.z * 512] = tob(v);
          }
        }
      }
    }
  }
}

// ---- split-K combine: ss[:, :512] = p0 + p1 + gates·b2 ----
__global__ __launch_bounds__(256) void combine_k(bf16* ss, const float* gates, const float* sb2) {
  long i = (long)blockIdx.x * 256 + threadIdx.x;
  int r = (int)(i >> 6);
  int c8 = (int)(i & 63) * 8;
  short8 p0 = *(const short8*)(ss + (long)r * 1024 + c8);
  short8 p1 = *(const short8*)(ss + (long)r * 1024 + 512 + c8);
  const float* gr = gates + (long)r * 4;
  float g0 = gr[0], g1 = gr[1], g2 = gr[2], g3 = gr[3];
  short8 o;
#pragma unroll
  for (int j = 0; j < 8; j++) {
    int c = c8 + j;
    float v = b2f(p0[j]) + b2f(p1[j]) + g0 * sb2[c] + g1 * sb2[512 + c] + g2 * sb2[1024 + c] +
              g3 * sb2[1536 + c];
    o[j] = __builtin_bit_cast(short, tob(v));
  }
  *(short8*)(ss + (long)r * 1024 + c8) = o;
}

// =====================  small kernels  =====================
__global__ __launch_bounds__(256) void gates_k(const bf16* x, const float* gw, const float* gb,
                                               float* gates) {
  int b = blockIdx.x * 4 + (threadIdx.x >> 6);
  int l = threadIdx.x & 63;
  short8 xv = *(const short8*)(x + (long)b * cD + l * 8);
  float a0 = 0, a1 = 0, a2 = 0, a3 = 0;
#pragma unroll
  for (int j = 0; j < 8; j++) {
    float xf = b2f(xv[j]);
    f32x4 wr = *(const f32x4*)(gw + (l * 8 + j) * 4);
    a0 += xf * wr[0];
    a1 += xf * wr[1];
    a2 += xf * wr[2];
    a3 += xf * wr[3];
  }
#pragma unroll
  for (int o = 32; o > 0; o >>= 1) {
    a0 += __shfl_xor(a0, o);
    a1 += __shfl_xor(a1, o);
    a2 += __shfl_xor(a2, o);
    a3 += __shfl_xor(a3, o);
  }
  a0 += gb[0];
  a1 += gb[1];
  a2 += gb[2];
  a3 += gb[3];
  float m = fmaxf(fmaxf(a0, a1), fmaxf(a2, a3));
  float e0 = expf(a0 - m), e1 = expf(a1 - m), e2 = expf(a2 - m), e3 = expf(a3 - m);
  float s = e0 + e1 + e2 + e3;
  if (l == 0) {
    float* gp = gates + (long)b * 4;
    gp[0] = e0 / s;
    gp[1] = e1 / s;
    gp[2] = e2 / s;
    gp[3] = e3 / s;
  }
}

__global__ __launch_bounds__(256) void bhist_k(const int* sid, int* bh) {
  int blk = blockIdx.x, t = threadIdx.x;
  __shared__ int h[cS];
  if (t < cS) h[t] = 0;
  __syncthreads();
  int s = sid[blk * 256 + t];
#pragma unroll
  for (int q = 0; q < cS; q++) {
    unsigned long long m = __ballot(s == q);
    if ((t & 63) == 0) atomicAdd(&h[q], __popcll(m));
  }
  __syncthreads();
  if (t < cS) bh[blk * cS + t] = h[t];
}

__global__ void bbase_k(const int* bh, int* base, int* cum) {
  __shared__ int tot[cS];
  int s = threadIdx.x;
  if (s < cS) {
    int run = 0;
    for (int b = 0; b < 64; b++) {
      base[b * cS + s] = run;
      run += bh[b * cS + s];
    }
    tot[s] = run;
  }
  __syncthreads();
  if (s == 0) {
    int run = 0;
    for (int q = 0; q < cS; q++) {
      cum[q] = run;
      run += tot[q];
    }
    cum[cS] = run;
  }
  __syncthreads();
  if (s < cS) {
    int c = cum[s];
    for (int b = 0; b < 64; b++) base[b * cS + s] += c;
  }
}

__global__ __launch_bounds__(256) void bscat_k(const int* sid, const int* base, int* perm) {
  int blk = blockIdx.x, t = threadIdx.x, w = t >> 6, l = t & 63;
  __shared__ int wc[4][cS];
  __shared__ int wb[4][cS];
  int s = sid[blk * 256 + t];
  int rank = 0;
#pragma unroll
  for (int q = 0; q < cS; q++) {
    unsigned long long m = __ballot(s == q);
    if (l == 0) wc[w][q] = __popcll(m);
    if (s == q) rank = __popcll(m & ((1ull << l) - 1ull));
  }
  __syncthreads();
  if (t < cS) {
    int run = 0;
#pragma unroll
    for (int ww = 0; ww < 4; ww++) {
      wb[ww][t] = run;
      run += wc[ww][t];
    }
  }
  __syncthreads();
  perm[base[blk * cS + s] + wb[w][s] + rank] = blk * 256 + t;
}

__global__ __launch_bounds__(256) void scenpart_k(const float* emb, const float* w1,
                                                  const float* b1, float* scp) {
  __shared__ float red[8][32];
  int s = blockIdx.x;
  int nl = threadIdx.x & 31;
  int n = blockIdx.y * 32 + nl;
  int dg = threadIdx.x >> 5;
  float a = 0.f;
#pragma unroll 4
  for (int d = dg * 64; d < dg * 64 + 64; d++) a += emb[s * cD + d] * w1[(long)(cD + d) * cDH + n];
  red[dg][nl] = a;
  __syncthreads();
  if (dg == 0) {
    float t = b1[n];
#pragma unroll
    for (int g = 0; g < 8; g++) t += red[g][nl];
    scp[s * cDH + n] = t;
  }
}

__global__ __launch_bounds__(256) void wsel_k(const float* sp, const float* scp, const float* w2,
                                              const int* sid, float* wsel) {
  int b = blockIdx.x * 4 + (threadIdx.x >> 6);
  int l = threadIdx.x & 63;
  float spv[4], w2v[4];
#pragma unroll
  for (int q = 0; q < 4; q++) {
    spv[q] = sp[(long)b * cDH + q * 64 + l];
    w2v[q] = w2[q * 64 + l];
  }
  float lg[8];
#pragma unroll
  for (int s = 0; s < 8; s++) {
    float acc = 0.f;
#pragma unroll
    for (int q = 0; q < 4; q++) {
      float v = spv[q] + scp[s * cDH + q * 64 + l];
      v = fmaxf(v, 0.f);
      acc += v * w2v[q];
    }
#pragma unroll
    for (int o = 32; o > 0; o >>= 1) acc += __shfl_xor(acc, o);
    lg[s] = acc;
  }
  float m = lg[0];
#pragma unroll
  for (int s = 1; s < 8; s++) m = fmaxf(m, lg[s]);
  float sum = 0.f;
#pragma unroll
  for (int s = 0; s < 8; s++) sum += expf(lg[s] - m);
  if (l == 0) {
    int s0 = sid[b];
    wsel[b] = expf(lg[s0] - m) / sum;
  }
}

__global__ __launch_bounds__(256) void cvt_shared_k(const float* sf, bf16* ss) {
  int i = blockIdx.x * 256 + threadIdx.x;
  int r = i >> 7, c = (i & 127) * 4;
  f32x4 v = *(const f32x4*)(sf + (long)r * cD + c);
  short4v o;
#pragma unroll
  for (int j = 0; j < 4; j++) o[j] = __builtin_bit_cast(short, tob(v[j]));
  *(short4v*)(ss + (long)r * 1024 + c) = o;
}

// =====================  launcher  =====================
extern "C" void kernel_launch(void* const* d_in, const int* in_sizes, int n_in, void* d_out,
                              int out_size, void* d_ws, size_t ws_size, hipStream_t stream) {
  const void* x = d_in[0];
  const int* sid = (const int*)d_in[1];

  char* ws = (char*)d_ws;
  size_t off = 0;
  auto alloc = [&](size_t bytes) -> void* {
    void* p = ws + off;
    off += (bytes + 255) & ~(size_t)255;
    return p;
  };
  int* g_flag = (int*)alloc(64);
  float* g_gates = (float*)alloc((size_t)cB * 4 * 4);
  float* g_wsel = (float*)alloc((size_t)cB * 4);
  int* g_perm = (int*)alloc((size_t)cB * 4);
  int* g_bh = (int*)alloc(64 * cS * 4);
  int* g_base = (int*)alloc(64 * cS * 4);
  int* g_cum = (int*)alloc(64);
  float* g_scp = (float*)alloc((size_t)cS * cDH * 4);
  float* g_small = (float*)alloc((size_t)300000 * 4);
  bf16* g_xb = (bf16*)alloc((size_t)cB * cD * 2);
  bf16* w1t = (bf16*)alloc((size_t)cE * cH * cD * 2);
  bf16* w2cat = (bf16*)alloc((size_t)cD * 4096 * 2);
  bf16* s1t = (bf16*)alloc((size_t)cS * cH * cD * 2);
  bf16* s2t = (bf16*)alloc((size_t)cS * cD * cH * 2);
  bf16* a1t = (bf16*)alloc((size_t)cDH * cD * 2);
  bf16* owpair = (bf16*)alloc((size_t)1024 * 1024 * 2);
  bf16* g_ss = (bf16*)alloc((size_t)cB * 1024 * 2);
  size_t fixed_end = off;
  const size_t MB = 1024ull * 1024ull;
  const bool BIG = (ws_size == 0) || (fixed_end + 135 * MB <= ws_size);
  char* g_big = (char*)alloc(BIG ? 135 * MB : 68 * MB);
  (void)in_sizes;
  (void)n_in;
  (void)out_size;

  // opt-in 128KB dynamic LDS for the 256^2 engine; legacy fallback if refused
  bool use256 = true;
  use256 &= hipFuncSetAttribute(reinterpret_cast<const void*>(g256_k<6>),
                                hipFuncAttributeMaxDynamicSharedMemorySize, 131072) == hipSuccess;
  use256 &= hipFuncSetAttribute(reinterpret_cast<const void*>(g256_k<8>),
                                hipFuncAttributeMaxDynamicSharedMemorySize, 131072) == hipSuccess;
  use256 &= hipFuncSetAttribute(reinterpret_cast<const void*>(g256_k<9>),
                                hipFuncAttributeMaxDynamicSharedMemorySize, 131072) == hipSuccess;

  dim3 blk(256);
  probe_k<<<1, blk, 0, stream>>>(x, g_flag);
  cvtx_k<<<cB * cD / 8 / 256, blk, 0, stream>>>(x, g_xb, g_flag);

  const int O_GW = 0, O_GB = 2048, O_SB1 = 2052, O_SB2 = 6148, O_PB1 = 8196, O_PB2 = 16388,
            O_EMB = 20484, O_AW1 = 24580, O_AB1 = 286724, O_AW2 = 286980, O_OB = 287236,
            O_END = 287748;
  {
    CvtDesc d;
    const void* srcs[11] = {d_in[2],  d_in[3],  d_in[5],  d_in[7],  d_in[9], d_in[11],
                            d_in[12], d_in[13], d_in[14], d_in[15], d_in[18]};
    int offs[12] = {O_GW, O_GB, O_SB1, O_SB2, O_PB1, O_PB2, O_EMB, O_AW1, O_AB1, O_AW2, O_OB,
                    O_END};
    for (int i = 0; i < 11; i++) d.src[i] = srcs[i];
    for (int i = 0; i < 12; i++) d.off[i] = offs[i];
    cvt_smalls_k<<<(O_END + 255) / 256, blk, 0, stream>>>(d, g_flag, g_small);
  }

  transpose_k<<<dim3(cH / 32, cD / 32, cE), blk, 0, stream>>>(d_in[4], w1t, cH, cD, 0,
                                                              (long)cD * cH, (long)cH * cD, g_flag);
  transpose_k<<<dim3(cD / 32, cH / 32, cE), blk, 0, stream>>>(d_in[6], w2cat, cD, 4096, 0,
                                                              (long)cH * cD, 1024, g_flag);
  transpose_k<<<dim3(cH / 32, cD / 32, cS), blk, 0, stream>>>(d_in[8], s1t, cH, cD, 0,
                                                              (long)cD * cH, (long)cH * cD, g_flag);
  transpose_k<<<dim3(cD / 32, cH / 32, cS), blk, 0, stream>>>(d_in[10], s2t, cD, cH, 0,
                                                              (long)cH * cD, (long)cD * cH, g_flag);
  transpose_k<<<dim3(cDH / 32, cD / 32, 1), blk, 0, stream>>>(d_in[13], a1t, cDH, cD, 0, 0, 0,
                                                              g_flag);
  owt_k<<<dim3(cD / 32, cD / 32, 4), blk, 0, stream>>>(d_in[17], owpair, g_flag);

  gates_k<<<cB / 4, blk, 0, stream>>>(g_xb, g_small + O_GW, g_small + O_GB, g_gates);
  bhist_k<<<cB / 256, blk, 0, stream>>>(sid, g_bh);
  bbase_k<<<1, 64, 0, stream>>>(g_bh, g_base, g_cum);
  bscat_k<<<cB / 256, blk, 0, stream>>>(sid, g_base, g_perm);

  if (BIG) {
    bf16* h4 = (bf16*)g_big;     // [16384,4096]
    float* sp = (float*)g_big;   // [16384,256] (after h4 dead)
    bf16* hspec = (bf16*)g_big;  // [16384,1024] (after sp dead)
    // GEMM1: x @ w1t -> h4 (gated relu)
    if (use256) {
      G6Args a{};
      a.A = g_xb; a.lda = cD; a.Bt = w1t; a.ldb = cD;
      a.C = h4; a.ldc = 4096; a.N = 4096; a.K = cD;
      a.bias = g_small + O_SB1; a.gates = g_gates;
      g256_k<6><<<dim3(16, 64), 512, 131072, stream>>>(a);
    } else {
      GArgs a{};
      a.A = g_xb; a.lda = cD; a.Bt = w1t; a.ldb = cD;
      a.C = h4; a.ldc = 4096; a.M = cB; a.N = 4096; a.K = cD;
      a.bias = g_small + O_SB1; a.gates = g_gates;
      gemm_k<6, false, false, false><<<dim3(32, cB / 128), blk, 0, stream>>>(a);
    }
    // GEMM2: h4 @ w2cat, split-K=2 -> raw bf16 partials in ss cols [z*512, ...)
    if (use256) {
      G6Args a{};
      a.A = h4; a.lda = 4096; a.Bt = w2cat; a.ldb = 4096;
      a.C = g_ss; a.ldc = 1024; a.N = cD; a.K = 2048;
      g256_k<8><<<dim3(2, 64, 2), 512, 131072, stream>>>(a);
    } else {
      GArgs a{};
      a.A = h4; a.lda = 4096; a.Bt = w2cat; a.ldb = 4096;
      a.C = g_ss; a.ldc = 1024; a.M = cB; a.N = cD; a.K = 2048;
      a.eidx = 512;
      gemm_k<8, false, false, false, true><<<dim3(cD / 128, cB / 128, 2), blk, 0, stream>>>(a);
    }
    combine_k<<<cB * 64 / 256, blk, 0, stream>>>(g_ss, g_gates, g_small + O_SB2);
    {
      GArgs a{};
      a.A = g_ss; a.lda = 1024; a.Bt = a1t; a.ldb = cD;
      a.C = sp; a.ldc = cDH; a.M = cB; a.N = cDH; a.K = cD;
      gemm_k<3, false, false, false><<<dim3(cDH / 128, cB / 128), blk, 0, stream>>>(a);
    }
    scenpart_k<<<dim3(cS, 8), blk, 0, stream>>>(g_small + O_EMB, g_small + O_AW1, g_small + O_AB1,
                                                g_scp);
    wsel_k<<<cB / 4, blk, 0, stream>>>(sp, g_scp, g_small + O_AW2, sid, g_wsel);
    {
      GArgs a{};
      a.A = g_xb; a.lda = cD; a.Bt = s1t; a.ldb = cD; a.bt_stride = (long)cH * cD;
      a.C = hspec; a.ldc = cH; a.M = cB; a.N = cH; a.K = cD;
      a.bias = g_small + O_PB1; a.bias_stride = cH;
      a.perm = g_perm; a.cum = g_cum;
      gemm_k<1, true, true, false><<<dim3(cH / 128, cB / 128, cS), blk, 0, stream>>>(a);
    }
    {
      GArgs a{};
      a.A = hspec; a.lda = cH; a.Bt = s2t; a.ldb = cH; a.bt_stride = (long)cD * cH;
      a.C = g_ss + 512; a.ldc = 1024; a.M = cB; a.N = cD; a.K = cH;
      a.bias = g_small + O_PB2; a.bias_stride = cD;
      a.perm = g_perm; a.cum = g_cum;
      gemm_k<4, true, false, true><<<dim3(cD / 128, cB / 128, cS), blk, 0, stream>>>(a);
    }
    // merged P1+out
    if (use256) {
      G6Args a{};
      a.A = g_ss; a.lda = 1024; a.Bt = owpair; a.ldb = 1024;
      a.C = d_out; a.ldc = cD; a.N = 1024; a.K = 1024;
      a.bias = g_small + O_OB; a.wsel = g_wsel; a.dflag = g_flag;
      g256_k<9><<<dim3(4, 64), 512, 131072, stream>>>(a);
    } else {
      GArgs a{};
      a.A = g_ss; a.lda = 1024; a.Bt = owpair; a.ldb = 1024;
      a.C = d_out; a.ldc = cD; a.M = cB; a.N = 1024; a.K = 1024;
      a.bias = g_small + O_OB; a.wsel = g_wsel; a.dflag = g_flag;
      gemm_k<9, false, false, false><<<dim3(8, cB / 128), blk, 0, stream>>>(a);
    }
  } else {
    // fallback: sequential-expert structure inside 68MB scratch
    float* f32a = (float*)g_big;            // [16384,512] f32
    bf16* hbuf = (bf16*)(g_big + 34 * MB);  // [16384,1024] bf16
    for (int e = 0; e < cE; e++) {
      GArgs a1{};
      a1.A = g_xb; a1.lda = cD; a1.Bt = w1t + (size_t)e * cH * cD; a1.ldb = cD;
      a1.C = hbuf; a1.ldc = cH; a1.M = cB; a1.N = cH; a1.K = cD;
      a1.bias = g_small + O_SB1 + e * cH;
      gemm_k<1, false, false, false><<<dim3(cH / 128, cB / 128), blk, 0, stream>>>(a1);
      GArgs a2{};
      a2.A = hbuf; a2.lda = cH; a2.Bt = w2cat + (size_t)e * 1024; a2.ldb = 4096;
      a2.C = f32a; a2.ldc = cD; a2.M = cB; a2.N = cD; a2.K = cH;
      a2.bias = g_small + O_SB2 + e * cD; a2.gates = g_gates; a2.eidx = e;
      gemm_k<2, false, false, false><<<dim3(cD / 128, cB / 128), blk, 0, stream>>>(a2);
    }
    cvt_shared_k<<<cB * 128 / 256, blk, 0, stream>>>(f32a, g_ss);
    {
      GArgs a{};
      a.A = g_xb; a.lda = cD; a.Bt = s1t; a.ldb = cD; a.bt_stride = (long)cH * cD;
      a.C = hbuf; a.ldc = cH; a.M = cB; a.N = cH; a.K = cD;
      a.bias = g_small + O_PB1; a.bias_stride = cH;
      a.perm = g_perm; a.cum = g_cum;
      gemm_k<1, true, true, false><<<dim3(cH / 128, cB / 128, cS), blk, 0, stream>>>(a);
    }
    {
      GArgs a{};
      a.A = hbuf; a.lda = cH; a.Bt = s2t; a.ldb = cH; a.bt_stride = (long)cD * cH;
      a.C = g_ss + 512; a.ldc = 1024; a.M = cB; a.N = cD; a.K = cH;
      a.bias = g_small + O_PB2; a.bias_stride = cD;
      a.perm = g_perm; a.cum = g_cum;
      gemm_k<4, true, false, true><<<dim3(cD / 128, cB / 128, cS), blk, 0, stream>>>(a);
    }
    {
      GArgs a{};
      a.A = g_ss; a.lda = 1024; a.Bt = a1t; a.ldb = cD;
      a.C = f32a; a.ldc = cDH; a.M = cB; a.N = cDH; a.K = cD;
      gemm_k<3, false, false, false><<<dim3(cDH / 128, cB / 128), blk, 0, stream>>>(a);
    }
    scenpart_k<<<dim3(cS, 8), blk, 0, stream>>>(g_small + O_EMB, g_small + O_AW1, g_small + O_AB1,
                                                g_scp);
    wsel_k<<<cB / 4, blk, 0, stream>>>(f32a, g_scp, g_small + O_AW2, sid, g_wsel);
    {
      GArgs a{};
      a.A = g_ss; a.lda = 1024; a.Bt = owpair; a.ldb = 1024;
      a.C = d_out; a.ldc = cD; a.M = cB; a.N = 1024; a.K = 1024;
      a.bias = g_small + O_OB; a.wsel = g_wsel; a.dflag = g_flag;
      gemm_k<9, false, false, false><<<dim3(8, cB / 128), blk, 0, stream>>>(a);
    }
  }
}

// Round 12
// 398.211 us; speedup vs baseline: 1.0880x; 1.0193x over previous
//
#include <hip/hip_runtime.h>
#include <hip/hip_bf16.h>
#include <stdint.h>

typedef __hip_bfloat16 bf16;
typedef __attribute__((ext_vector_type(8))) short short8;
typedef __attribute__((ext_vector_type(4))) short short4v;
typedef __attribute__((ext_vector_type(4))) float f32x4;

constexpr int cB = 16384, cD = 512, cH = 1024, cS = 8, cE = 4, cDH = 256;

__device__ __forceinline__ float tof(bf16 v) { return __bfloat162float(v); }
__device__ __forceinline__ bf16 tob(float v) { return __float2bfloat16(v); }
__device__ __forceinline__ float b2f(short s) {
  uint32_t u = ((uint32_t)(uint16_t)s) << 16;
  return __builtin_bit_cast(float, u);
}
__device__ __forceinline__ float ldf(const void* p, long i, int isbf) {
  return isbf ? b2f(((const short*)p)[i]) : ((const float*)p)[i];
}
__device__ __forceinline__ void stbf_nt(bf16* p, float v) {
  __builtin_nontemporal_store(__builtin_bit_cast(short, tob(v)), (short*)p);
}

__device__ __forceinline__ void gload_lds16(const bf16* g, char* l) {
  __builtin_amdgcn_global_load_lds(
      (const __attribute__((address_space(1))) void*)g,
      (__attribute__((address_space(3))) void*)l, 16, 0, 0);
}

// ---- dtype probe ----
__global__ __launch_bounds__(256) void probe_k(const void* x, int* flag) {
  __shared__ int sh[256];
  const unsigned short* u = (const unsigned short*)x;
  int cnt = 0;
  for (int i = threadIdx.x; i < 2048; i += 256) {
    float v = fabsf(b2f((short)u[2 * i]));
    cnt += (v > 1e-5f && v < 1e3f) ? 1 : 0;
  }
  sh[threadIdx.x] = cnt;
  __syncthreads();
  for (int s = 128; s > 0; s >>= 1) {
    if (threadIdx.x < s) sh[threadIdx.x] += sh[threadIdx.x + s];
    __syncthreads();
  }
  if (threadIdx.x == 0) flag[0] = (sh[0] > 1024) ? 1 : 0;
}

__global__ __launch_bounds__(256) void cvtx_k(const void* x, bf16* xb, const int* flag) {
  int g = blockIdx.x * 256 + threadIdx.x;
  if (flag[0]) {
    ((short8*)xb)[g] = ((const short8*)x)[g];
  } else {
    const f32x4* xf = (const f32x4*)x;
    f32x4 v0 = xf[2 * g], v1 = xf[2 * g + 1];
    short8 o;
#pragma unroll
    for (int j = 0; j < 4; j++) {
      o[j] = __builtin_bit_cast(short, tob(v0[j]));
      o[j + 4] = __builtin_bit_cast(short, tob(v1[j]));
    }
    ((short8*)xb)[g] = o;
  }
}

struct CvtDesc {
  const void* src[11];
  int off[12];
};
__global__ __launch_bounds__(256) void cvt_smalls_k(CvtDesc d, const int* flag, float* dst) {
  int i = blockIdx.x * 256 + threadIdx.x;
  if (i >= d.off[11]) return;
  int isb = flag[0];
  int j = 0;
  while (i >= d.off[j + 1]) j++;
  dst[i] = ldf(d.src[j], i - d.off[j], isb);
}

__global__ __launch_bounds__(256) void transpose_k(const void* in, bf16* out, int ldin, int ldout,
                                                   long in_off, long in_bs, long out_bs,
                                                   const int* flag) {
  __shared__ float tile[32][33];
  int isb = flag[0];
  long src0 = in_off + (long)blockIdx.z * in_bs;
  bf16* dst = out + (long)blockIdx.z * out_bs;
  int c0 = blockIdx.x * 32, r0 = blockIdx.y * 32;
  int tx = threadIdx.x & 31, ty = threadIdx.x >> 5;
#pragma unroll
  for (int i = 0; i < 4; i++)
    tile[ty + i * 8][tx] = ldf(in, src0 + (long)(r0 + ty + i * 8) * ldin + c0 + tx, isb);
  __syncthreads();
#pragma unroll
  for (int i = 0; i < 4; i++)
    dst[(long)(c0 + ty + i * 8) * ldout + r0 + tx] = tob(tile[tx][ty + i * 8]);
}

// ---- out_w -> owpair: interleaved [W0;W2]^T / [W1;W3]^T rows (EPI9 pairing) ----
__global__ __launch_bounds__(256) void owt_k(const void* ow, bf16* owpair, const int* flag) {
  __shared__ float tile[32][33];
  int isb = flag[0];
  int z = blockIdx.z;
  int m = z & 1, kb = (z >> 1) * 512;
  long base = (long)z * 512 * cD;
  int c0 = blockIdx.x * 32, r0 = blockIdx.y * 32;
  int tx = threadIdx.x & 31, ty = threadIdx.x >> 5;
#pragma unroll
  for (int i = 0; i < 4; i++)
    tile[ty + i * 8][tx] = ldf(ow, base + (long)(r0 + ty + i * 8) * cD + c0 + tx, isb);
  __syncthreads();
#pragma unroll
  for (int i = 0; i < 4; i++) {
    int n = c0 + ty + i * 8;
    int R = ((n >> 6) << 7) + (((n >> 5) & 1) << 6) + (m << 5) + (((n >> 4) & 1) << 4) + (n & 15);
    owpair[(long)R * 1024 + kb + r0 + tx] = tob(tile[tx][ty + i * 8]);
  }
}

// ================  legacy 128x128 GEMM engine  ================
struct GArgs {
  const bf16* A; int lda;
  const bf16* Bt; int ldb; long bt_stride;
  void* C; int ldc;
  int M, N, K;
  const float* bias; int bias_stride;
  const float* gates; int eidx;  // eidx doubles as SPLITK C-col offset
  const int* perm; const int* cum;
  const float* wsel;
  const int* dflag;
};

template <int EPI, bool GROUPED, bool GATHER_A, bool SCATTER_C, bool SPLITK = false>
__global__ __launch_bounds__(256, 4) void gemm_k(GArgs a) {
  __shared__ char smem[32768];
  char* ldsA = smem;
  char* ldsB = smem + 16384;

  int bxs, bys;
  if constexpr (!GROUPED) {
    const int gx = gridDim.x;
    const int nwg = gx * gridDim.y;
    const int d = blockIdx.y * gx + blockIdx.x;
    const int q = nwg >> 3, r = nwg & 7;
    const int xcd = d & 7, di = d >> 3;
    const int logical = (xcd < r ? xcd * (q + 1) : r * (q + 1) + (xcd - r) * q) + di;
    bxs = logical % gx;
    bys = logical / gx;
  } else {
    bxs = blockIdx.x;
    bys = blockIdx.y;
  }

  int g0, cnt;
  if constexpr (GROUPED) {
    int z = blockIdx.z;
    g0 = a.cum[z];
    cnt = a.cum[z + 1] - g0;
  } else {
    g0 = 0;
    cnt = a.M;
  }
  const int ptile = bys * 128;
  if (ptile >= cnt) return;
  const int n0 = bxs * 128;
  const int zk = SPLITK ? blockIdx.z * a.K : 0;
  const int zc = SPLITK ? blockIdx.z * a.eidx : 0;

  const int t = threadIdx.x, w = t >> 6, l = t & 63;
  const int wm = w >> 1, wn = w & 1;

  const bf16* bt = a.Bt + (GROUPED ? (long)blockIdx.z * a.bt_stride : 0);
  const float* bias = a.bias ? (a.bias + (GROUPED ? blockIdx.z * a.bias_stride : 0)) : nullptr;

  const bf16* aSrc[4];
  const bf16* bSrc[4];
  int ldsOff[4];
#pragma unroll
  for (int c = 0; c < 4; c++) {
    int pos = w * 4096 + c * 1024 + l * 16;
    int row = pos >> 7;
    int su = ((((pos >> 4) & 7) ^ (row & 7))) * 8;
    int p = ptile + row;
    if (p > cnt - 1) p = cnt - 1;
    int ar;
    if constexpr (GATHER_A) ar = a.perm[g0 + p];
    else ar = g0 + p;
    aSrc[c] = a.A + (long)ar * a.lda + zk + su;
    bSrc[c] = bt + (long)(n0 + row) * a.ldb + zk + su;
    ldsOff[c] = w * 4096 + c * 1024;
  }

  f32x4 zero = {0.f, 0.f, 0.f, 0.f};
  f32x4 acc[4][4];
#pragma unroll
  for (int i = 0; i < 4; i++)
#pragma unroll
    for (int j = 0; j < 4; j++) acc[i][j] = zero;

  const int nkt = a.K >> 6;
  for (int kt = 0; kt < nkt; ++kt) {
#pragma unroll
    for (int c = 0; c < 4; c++) gload_lds16(aSrc[c] + kt * 64, ldsA + ldsOff[c]);
#pragma unroll
    for (int c = 0; c < 4; c++) gload_lds16(bSrc[c] + kt * 64, ldsB + ldsOff[c]);
    __syncthreads();
#pragma unroll
    for (int kk = 0; kk < 2; kk++) {
      short8 af[4], bv[4];
#pragma unroll
      for (int mi = 0; mi < 4; mi++) {
        int row = wm * 64 + mi * 16 + (l & 15);
        int kg = kk * 4 + (l >> 4);
        int off = row * 128 + ((kg ^ (row & 7)) << 4);
        af[mi] = *(const short8*)(ldsA + off);
      }
#pragma unroll
      for (int ni = 0; ni < 4; ni++) {
        int row = wn * 64 + ni * 16 + (l & 15);
        int kg = kk * 4 + (l >> 4);
        int off = row * 128 + ((kg ^ (row & 7)) << 4);
        bv[ni] = *(const short8*)(ldsB + off);
      }
#pragma unroll
      for (int mi = 0; mi < 4; mi++)
#pragma unroll
        for (int ni = 0; ni < 4; ni++)
          acc[mi][ni] =
              __builtin_amdgcn_mfma_f32_16x16x32_bf16(af[mi], bv[ni], acc[mi][ni], 0, 0, 0);
    }
    __syncthreads();
  }

  const int l15 = l & 15, lg4 = l >> 4;
  int outbf = 1;
  if constexpr (EPI == 9) outbf = a.dflag[0];
#pragma unroll
  for (int mi = 0; mi < 4; mi++) {
#pragma unroll
    for (int j = 0; j < 4; j++) {
      int p = ptile + wm * 64 + mi * 16 + lg4 * 4 + j;
      if (p >= cnt) continue;
      int crow;
      if constexpr (SCATTER_C) crow = a.perm[g0 + p];
      else crow = g0 + p;
      if constexpr (EPI == 9) {
        float wv = a.wsel[crow];
#pragma unroll
        for (int ni = 0; ni < 2; ni++) {
          int n = (n0 >> 1) + wn * 32 + ni * 16 + l15;
          float o = acc[mi][ni][j] + wv * acc[mi][ni + 2][j] + a.bias[n];
          if (outbf) ((bf16*)a.C)[(long)crow * a.ldc + n] = tob(o);
          else ((float*)a.C)[(long)crow * a.ldc + n] = o;
        }
        continue;
      }
#pragma unroll
      for (int ni = 0; ni < 4; ni++) {
        int n = n0 + wn * 64 + ni * 16 + l15;
        float v = acc[mi][ni][j];
        if constexpr (EPI == 1) {
          v += bias[n];
          v = fmaxf(v, 0.f);
          stbf_nt(&((bf16*)a.C)[(long)crow * a.ldc + n], v);
        } else if constexpr (EPI == 2) {
          float g = a.gates[(long)(g0 + p) * 4 + a.eidx];
          v = g * (v + bias[n]);
          float* Cf = (float*)a.C;
          long idx = (long)crow * a.ldc + n;
          if (a.eidx == 0) Cf[idx] = v;
          else Cf[idx] += v;
        } else if constexpr (EPI == 3) {
          ((float*)a.C)[(long)crow * a.ldc + n] = v;
        } else if constexpr (EPI == 4) {
          v += bias[n];
          ((bf16*)a.C)[(long)crow * a.ldc + n] = tob(v);
        } else if constexpr (EPI == 6) {
          float g = a.gates[(long)(g0 + p) * 4 + (n >> 10)];
          v = g * fmaxf(v + bias[n], 0.f);
          stbf_nt(&((bf16*)a.C)[(long)crow * a.ldc + n], v);
        } else if constexpr (EPI == 7) {
          const float* gr = a.gates + (long)(g0 + p) * 4;
          v += gr[0] * bias[n] + gr[1] * bias[512 + n] + gr[2] * bias[1024 + n] +
               gr[3] * bias[1536 + n];
          ((bf16*)a.C)[(long)crow * a.ldc + n] = tob(v);
        } else if constexpr (EPI == 8) {
          ((bf16*)a.C)[(long)crow * a.ldc + n + zc] = tob(v);
        }
      }
    }
  }
}

// ============  256x256 phase-interleaved engine (T2+T3+T4+T5)  ============
// Used where it measured faster than legacy (r10): GEMM2 split-K and merged
// EPI9 (long-K, small-N). GEMM1 stays legacy (r10: 102 vs <=94 us — short K
// and 1-block/CU occupancy hurt the deep pipeline there).
struct G6Args {
  const bf16* A; int lda;
  const bf16* Bt; int ldb;
  void* C; int ldc;
  int N, K;
  const float* bias;
  const float* gates;
  const float* wsel;
  const int* dflag;
};

template <int EPI>
__global__ __launch_bounds__(512, 1) void g256_k(G6Args a) {
  extern __shared__ char sm[];
  const int t = threadIdx.x, w = t >> 6, l = t & 63;
  const int wm = w >> 2, wn = w & 3;

  const int gx = gridDim.x, nwg = gx * gridDim.y;
  const int dd = blockIdx.y * gx + blockIdx.x;
  const int q = nwg >> 3, r = nwg & 7;
  const int xcd = dd & 7, di = dd >> 3;
  const int logical = (xcd < r ? xcd * (q + 1) : r * (q + 1) + (xcd - r) * q) + di;
  const int m0 = (logical / gx) * 256, n0 = (logical % gx) * 256;
  const long zk = (long)blockIdx.z * a.K;

  const bf16* srcP[8];
  int ldsO[8];
#pragma unroll
  for (int c = 0; c < 8; c++) {
    int pos = (c & 3) * 8192 + t * 16;
    int row = pos >> 7;
    int su = (((pos >> 4) & 7) ^ (row & 7)) * 8;
    if (c < 4) {
      srcP[c] = a.A + (long)(m0 + row) * a.lda + zk + su;
      ldsO[c] = (c & 3) * 8192 + w * 1024;
    } else {
      srcP[c] = a.Bt + (long)(n0 + row) * a.ldb + zk + su;
      ldsO[c] = 32768 + (c & 3) * 8192 + w * 1024;
    }
  }

  auto rdA = [&](char* buf, int mi, int kk) -> short8 {
    int row = wm * 128 + mi * 16 + (l & 15);
    int kg = kk * 4 + (l >> 4);
    return *(const short8*)(buf + row * 128 + ((kg ^ (row & 7)) << 4));
  };
  auto rdB = [&](char* buf, int ni, int kk) -> short8 {
    int row = wn * 64 + ni * 16 + (l & 15);
    int kg = kk * 4 + (l >> 4);
    return *(const short8*)(buf + 32768 + row * 128 + ((kg ^ (row & 7)) << 4));
  };

  f32x4 acc[8][4];
#pragma unroll
  for (int i = 0; i < 8; i++)
#pragma unroll
    for (int j = 0; j < 4; j++) acc[i][j] = {0.f, 0.f, 0.f, 0.f};

  const int nkt = a.K >> 6;
#pragma unroll
  for (int c = 0; c < 8; c++) gload_lds16(srcP[c], sm + ldsO[c]);
#pragma unroll
  for (int c = 0; c < 8; c++) gload_lds16(srcP[c] + 64, sm + 65536 + ldsO[c]);

  for (int kt = 0; kt < nkt; ++kt) {
    char* buf = sm + (kt & 1) * 65536;
    if (kt + 1 < nkt) asm volatile("s_waitcnt vmcnt(8)" ::: "memory");
    else asm volatile("s_waitcnt vmcnt(0)" ::: "memory");
    __builtin_amdgcn_s_barrier();

    const bool st = (kt + 2 < nkt);
    const int ko = (kt + 2) * 64;
    short8 fa[4][2], fb0[2][2], fb1[2][2];

    // P1: read A-lo + B ni0-1; MFMA (mi0-3 x ni0-1)
#pragma unroll
    for (int mi = 0; mi < 4; mi++)
#pragma unroll
      for (int kk = 0; kk < 2; kk++) fa[mi][kk] = rdA(buf, mi, kk);
#pragma unroll
    for (int ni = 0; ni < 2; ni++)
#pragma unroll
      for (int kk = 0; kk < 2; kk++) fb0[ni][kk] = rdB(buf, ni, kk);
    __builtin_amdgcn_s_barrier();
    asm volatile("s_waitcnt lgkmcnt(0)" ::: "memory");
    __builtin_amdgcn_s_setprio(1);
#pragma unroll
    for (int mi = 0; mi < 4; mi++)
#pragma unroll
      for (int ni = 0; ni < 2; ni++)
#pragma unroll
        for (int kk = 0; kk < 2; kk++)
          acc[mi][ni] =
              __builtin_amdgcn_mfma_f32_16x16x32_bf16(fa[mi][kk], fb0[ni][kk], acc[mi][ni], 0, 0, 0);
    __builtin_amdgcn_s_setprio(0);
    __builtin_amdgcn_s_barrier();

    // P2: read B ni2-3; stage Aq0,Aq2; MFMA (mi0-3 x ni2-3)
#pragma unroll
    for (int ni = 0; ni < 2; ni++)
#pragma unroll
      for (int kk = 0; kk < 2; kk++) fb1[ni][kk] = rdB(buf, ni + 2, kk);
    if (st) {
      gload_lds16(srcP[0] + ko, buf + ldsO[0]);
      gload_lds16(srcP[2] + ko, buf + ldsO[2]);
    }
    __builtin_amdgcn_s_barrier();
    asm volatile("s_waitcnt lgkmcnt(0)" ::: "memory");
    __builtin_amdgcn_s_setprio(1);
#pragma unroll
    for (int mi = 0; mi < 4; mi++)
#pragma unroll
      for (int ni = 0; ni < 2; ni++)
#pragma unroll
        for (int kk = 0; kk < 2; kk++)
          acc[mi][ni + 2] = __builtin_amdgcn_mfma_f32_16x16x32_bf16(fa[mi][kk], fb1[ni][kk],
                                                                    acc[mi][ni + 2], 0, 0, 0);
    __builtin_amdgcn_s_setprio(0);
    __builtin_amdgcn_s_barrier();

    // P3: read A-hi; stage Bq0-3; MFMA (mi4-7 x ni0-1)
#pragma unroll
    for (int mi = 0; mi < 4; mi++)
#pragma unroll
      for (int kk = 0; kk < 2; kk++) fa[mi][kk] = rdA(buf, mi + 4, kk);
    if (st) {
      gload_lds16(srcP[4] + ko, buf + ldsO[4]);
      gload_lds16(srcP[5] + ko, buf + ldsO[5]);
      gload_lds16(srcP[6] + ko, buf + ldsO[6]);
      gload_lds16(srcP[7] + ko, buf + ldsO[7]);
    }
    __builtin_amdgcn_s_barrier();
    asm volatile("s_waitcnt lgkmcnt(0)" ::: "memory");
    __builtin_amdgcn_s_setprio(1);
#pragma unroll
    for (int mi = 0; mi < 4; mi++)
#pragma unroll
      for (int ni = 0; ni < 2; ni++)
#pragma unroll
        for (int kk = 0; kk < 2; kk++)
          acc[mi + 4][ni] = __builtin_amdgcn_mfma_f32_16x16x32_bf16(fa[mi][kk], fb0[ni][kk],
                                                                    acc[mi + 4][ni], 0, 0, 0);
    __builtin_amdgcn_s_setprio(0);
    __builtin_amdgcn_s_barrier();

    // P4: stage Aq1,Aq3; MFMA (mi4-7 x ni2-3)
    if (st) {
      gload_lds16(srcP[1] + ko, buf + ldsO[1]);
      gload_lds16(srcP[3] + ko, buf + ldsO[3]);
    }
    __builtin_amdgcn_s_barrier();
    __builtin_amdgcn_s_setprio(1);
#pragma unroll
    for (int mi = 0; mi < 4; mi++)
#pragma unroll
      for (int ni = 0; ni < 2; ni++)
#pragma unroll
        for (int kk = 0; kk < 2; kk++)
          acc[mi + 4][ni + 2] = __builtin_amdgcn_mfma_f32_16x16x32_bf16(
              fa[mi][kk], fb1[ni][kk], acc[mi + 4][ni + 2], 0, 0, 0);
    __builtin_amdgcn_s_setprio(0);
    __builtin_amdgcn_s_barrier();
  }

  const int l15 = l & 15, lg4 = l >> 4;
  int outbf = 1;
  if constexpr (EPI == 9) outbf = a.dflag[0];
#pragma unroll
  for (int mi = 0; mi < 8; mi++) {
#pragma unroll
    for (int j = 0; j < 4; j++) {
      int crow = m0 + wm * 128 + mi * 16 + lg4 * 4 + j;
      if constexpr (EPI == 9) {
        float wv = a.wsel[crow];
#pragma unroll
        for (int ni = 0; ni < 2; ni++) {
          int R = n0 + wn * 64 + ni * 16 + l15;
          int n = ((R >> 7) << 6) | (((R >> 6) & 1) << 5) | (((R >> 4) & 1) << 4) | (R & 15);
          float o = acc[mi][ni][j] + wv * acc[mi][ni + 2][j] + a.bias[n];
          if (outbf) ((bf16*)a.C)[(long)crow * a.ldc + n] = tob(o);
          else ((float*)a.C)[(long)crow * a.ldc + n] = o;
        }
      } else {
#pragma unroll
        for (int ni = 0; ni < 4; ni++) {
          int n = n0 + wn * 64 + ni * 16 + l15;
          float v = acc[mi][ni][j];
          if constexpr (EPI == 6) {
            float g = a.gates[(long)crow * 4 + (n >> 10)];
            v = g * fmaxf(v + a.bias[n], 0.f);
            stbf_nt(&((bf16*)a.C)[(long)crow * a.ldc + n], v);
          } else if constexpr (EPI == 8) {
            ((bf16*)a.C)[(long)crow * a.ldc + n + blockIdx.z * 512] = tob(v);
          }
        }
      }
    }
  }
}

// ---- split-K combine: ss[:, :512] = p0 + p1 + gates·b2 ----
__global__ __launch_bounds__(256) void combine_k(bf16* ss, const float* gates, const float* sb2) {
  long i = (long)blockIdx.x * 256 + threadIdx.x;
  int r = (int)(i >> 6);
  int c8 = (int)(i & 63) * 8;
  short8 p0 = *(const short8*)(ss + (long)r * 1024 + c8);
  short8 p1 = *(const short8*)(ss + (long)r * 1024 + 512 + c8);
  const float* gr = gates + (long)r * 4;
  float g0 = gr[0], g1 = gr[1], g2 = gr[2], g3 = gr[3];
  short8 o;
#pragma unroll
  for (int j = 0; j < 8; j++) {
    int c = c8 + j;
    float v = b2f(p0[j]) + b2f(p1[j]) + g0 * sb2[c] + g1 * sb2[512 + c] + g2 * sb2[1024 + c] +
              g3 * sb2[1536 + c];
    o[j] = __builtin_bit_cast(short, tob(v));
  }
  *(short8*)(ss + (long)r * 1024 + c8) = o;
}

// =====================  small kernels  =====================
__global__ __launch_bounds__(256) void gates_k(const bf16* x, const float* gw, const float* gb,
                                               float* gates) {
  int b = blockIdx.x * 4 + (threadIdx.x >> 6);
  int l = threadIdx.x & 63;
  short8 xv = *(const short8*)(x + (long)b * cD + l * 8);
  float a0 = 0, a1 = 0, a2 = 0, a3 = 0;
#pragma unroll
  for (int j = 0; j < 8; j++) {
    float xf = b2f(xv[j]);
    f32x4 wr = *(const f32x4*)(gw + (l * 8 + j) * 4);
    a0 += xf * wr[0];
    a1 += xf * wr[1];
    a2 += xf * wr[2];
    a3 += xf * wr[3];
  }
#pragma unroll
  for (int o = 32; o > 0; o >>= 1) {
    a0 += __shfl_xor(a0, o);
    a1 += __shfl_xor(a1, o);
    a2 += __shfl_xor(a2, o);
    a3 += __shfl_xor(a3, o);
  }
  a0 += gb[0];
  a1 += gb[1];
  a2 += gb[2];
  a3 += gb[3];
  float m = fmaxf(fmaxf(a0, a1), fmaxf(a2, a3));
  float e0 = expf(a0 - m), e1 = expf(a1 - m), e2 = expf(a2 - m), e3 = expf(a3 - m);
  float s = e0 + e1 + e2 + e3;
  if (l == 0) {
    float* gp = gates + (long)b * 4;
    gp[0] = e0 / s;
    gp[1] = e1 / s;
    gp[2] = e2 / s;
    gp[3] = e3 / s;
  }
}

__global__ __launch_bounds__(256) void bhist_k(const int* sid, int* bh) {
  int blk = blockIdx.x, t = threadIdx.x;
  __shared__ int h[cS];
  if (t < cS) h[t] = 0;
  __syncthreads();
  int s = sid[blk * 256 + t];
#pragma unroll
  for (int q = 0; q < cS; q++) {
    unsigned long long m = __ballot(s == q);
    if ((t & 63) == 0) atomicAdd(&h[q], __popcll(m));
  }
  __syncthreads();
  if (t < cS) bh[blk * cS + t] = h[t];
}

__global__ void bbase_k(const int* bh, int* base, int* cum) {
  __shared__ int tot[cS];
  int s = threadIdx.x;
  if (s < cS) {
    int run = 0;
    for (int b = 0; b < 64; b++) {
      base[b * cS + s] = run;
      run += bh[b * cS + s];
    }
    tot[s] = run;
  }
  __syncthreads();
  if (s == 0) {
    int run = 0;
    for (int q = 0; q < cS; q++) {
      cum[q] = run;
      run += tot[q];
    }
    cum[cS] = run;
  }
  __syncthreads();
  if (s < cS) {
    int c = cum[s];
    for (int b = 0; b < 64; b++) base[b * cS + s] += c;
  }
}

__global__ __launch_bounds__(256) void bscat_k(const int* sid, const int* base, int* perm) {
  int blk = blockIdx.x, t = threadIdx.x, w = t >> 6, l = t & 63;
  __shared__ int wc[4][cS];
  __shared__ int wb[4][cS];
  int s = sid[blk * 256 + t];
  int rank = 0;
#pragma unroll
  for (int q = 0; q < cS; q++) {
    unsigned long long m = __ballot(s == q);
    if (l == 0) wc[w][q] = __popcll(m);
    if (s == q) rank = __popcll(m & ((1ull << l) - 1ull));
  }
  __syncthreads();
  if (t < cS) {
    int run = 0;
#pragma unroll
    for (int ww = 0; ww < 4; ww++) {
      wb[ww][t] = run;
      run += wc[ww][t];
    }
  }
  __syncthreads();
  perm[base[blk * cS + s] + wb[w][s] + rank] = blk * 256 + t;
}

__global__ __launch_bounds__(256) void scenpart_k(const float* emb, const float* w1,
                                                  const float* b1, float* scp) {
  __shared__ float red[8][32];
  int s = blockIdx.x;
  int nl = threadIdx.x & 31;
  int n = blockIdx.y * 32 + nl;
  int dg = threadIdx.x >> 5;
  float a = 0.f;
#pragma unroll 4
  for (int d = dg * 64; d < dg * 64 + 64; d++) a += emb[s * cD + d] * w1[(long)(cD + d) * cDH + n];
  red[dg][nl] = a;
  __syncthreads();
  if (dg == 0) {
    float t = b1[n];
#pragma unroll
    for (int g = 0; g < 8; g++) t += red[g][nl];
    scp[s * cDH + n] = t;
  }
}

__global__ __launch_bounds__(256) void wsel_k(const float* sp, const float* scp, const float* w2,
                                              const int* sid, float* wsel) {
  int b = blockIdx.x * 4 + (threadIdx.x >> 6);
  int l = threadIdx.x & 63;
  float spv[4], w2v[4];
#pragma unroll
  for (int q = 0; q < 4; q++) {
    spv[q] = sp[(long)b * cDH + q * 64 + l];
    w2v[q] = w2[q * 64 + l];
  }
  float lg[8];
#pragma unroll
  for (int s = 0; s < 8; s++) {
    float acc = 0.f;
#pragma unroll
    for (int q = 0; q < 4; q++) {
      float v = spv[q] + scp[s * cDH + q * 64 + l];
      v = fmaxf(v, 0.f);
      acc += v * w2v[q];
    }
#pragma unroll
    for (int o = 32; o > 0; o >>= 1) acc += __shfl_xor(acc, o);
    lg[s] = acc;
  }
  float m = lg[0];
#pragma unroll
  for (int s = 1; s < 8; s++) m = fmaxf(m, lg[s]);
  float sum = 0.f;
#pragma unroll
  for (int s = 0; s < 8; s++) sum += expf(lg[s] - m);
  if (l == 0) {
    int s0 = sid[b];
    wsel[b] = expf(lg[s0] - m) / sum;
  }
}

__global__ __launch_bounds__(256) void cvt_shared_k(const float* sf, bf16* ss) {
  int i = blockIdx.x * 256 + threadIdx.x;
  int r = i >> 7, c = (i & 127) * 4;
  f32x4 v = *(const f32x4*)(sf + (long)r * cD + c);
  short4v o;
#pragma unroll
  for (int j = 0; j < 4; j++) o[j] = __builtin_bit_cast(short, tob(v[j]));
  *(short4v*)(ss + (long)r * 1024 + c) = o;
}

// =====================  launcher  =====================
extern "C" void kernel_launch(void* const* d_in, const int* in_sizes, int n_in, void* d_out,
                              int out_size, void* d_ws, size_t ws_size, hipStream_t stream) {
  const void* x = d_in[0];
  const int* sid = (const int*)d_in[1];

  char* ws = (char*)d_ws;
  size_t off = 0;
  auto alloc = [&](size_t bytes) -> void* {
    void* p = ws + off;
    off += (bytes + 255) & ~(size_t)255;
    return p;
  };
  int* g_flag = (int*)alloc(64);
  float* g_gates = (float*)alloc((size_t)cB * 4 * 4);
  float* g_wsel = (float*)alloc((size_t)cB * 4);
  int* g_perm = (int*)alloc((size_t)cB * 4);
  int* g_bh = (int*)alloc(64 * cS * 4);
  int* g_base = (int*)alloc(64 * cS * 4);
  int* g_cum = (int*)alloc(64);
  float* g_scp = (float*)alloc((size_t)cS * cDH * 4);
  float* g_small = (float*)alloc((size_t)300000 * 4);
  bf16* g_xb = (bf16*)alloc((size_t)cB * cD * 2);
  bf16* w1t = (bf16*)alloc((size_t)cE * cH * cD * 2);
  bf16* w2cat = (bf16*)alloc((size_t)cD * 4096 * 2);
  bf16* s1t = (bf16*)alloc((size_t)cS * cH * cD * 2);
  bf16* s2t = (bf16*)alloc((size_t)cS * cD * cH * 2);
  bf16* a1t = (bf16*)alloc((size_t)cDH * cD * 2);
  bf16* owpair = (bf16*)alloc((size_t)1024 * 1024 * 2);
  bf16* g_ss = (bf16*)alloc((size_t)cB * 1024 * 2);
  size_t fixed_end = off;
  const size_t MB = 1024ull * 1024ull;
  const bool BIG = (ws_size == 0) || (fixed_end + 135 * MB <= ws_size);
  char* g_big = (char*)alloc(BIG ? 135 * MB : 68 * MB);
  (void)in_sizes;
  (void)n_in;
  (void)out_size;

  bool use256 = true;
  use256 &= hipFuncSetAttribute(reinterpret_cast<const void*>(g256_k<8>),
                                hipFuncAttributeMaxDynamicSharedMemorySize, 131072) == hipSuccess;
  use256 &= hipFuncSetAttribute(reinterpret_cast<const void*>(g256_k<9>),
                                hipFuncAttributeMaxDynamicSharedMemorySize, 131072) == hipSuccess;

  dim3 blk(256);
  probe_k<<<1, blk, 0, stream>>>(x, g_flag);
  cvtx_k<<<cB * cD / 8 / 256, blk, 0, stream>>>(x, g_xb, g_flag);

  const int O_GW = 0, O_GB = 2048, O_SB1 = 2052, O_SB2 = 6148, O_PB1 = 8196, O_PB2 = 16388,
            O_EMB = 20484, O_AW1 = 24580, O_AB1 = 286724, O_AW2 = 286980, O_OB = 287236,
            O_END = 287748;
  {
    CvtDesc d;
    const void* srcs[11] = {d_in[2],  d_in[3],  d_in[5],  d_in[7],  d_in[9], d_in[11],
                            d_in[12], d_in[13], d_in[14], d_in[15], d_in[18]};
    int offs[12] = {O_GW, O_GB, O_SB1, O_SB2, O_PB1, O_PB2, O_EMB, O_AW1, O_AB1, O_AW2, O_OB,
                    O_END};
    for (int i = 0; i < 11; i++) d.src[i] = srcs[i];
    for (int i = 0; i < 12; i++) d.off[i] = offs[i];
    cvt_smalls_k<<<(O_END + 255) / 256, blk, 0, stream>>>(d, g_flag, g_small);
  }

  transpose_k<<<dim3(cH / 32, cD / 32, cE), blk, 0, stream>>>(d_in[4], w1t, cH, cD, 0,
                                                              (long)cD * cH, (long)cH * cD, g_flag);
  transpose_k<<<dim3(cD / 32, cH / 32, cE), blk, 0, stream>>>(d_in[6], w2cat, cD, 4096, 0,
                                                              (long)cH * cD, 1024, g_flag);
  transpose_k<<<dim3(cH / 32, cD / 32, cS), blk, 0, stream>>>(d_in[8], s1t, cH, cD, 0,
                                                              (long)cD * cH, (long)cH * cD, g_flag);
  transpose_k<<<dim3(cD / 32, cH / 32, cS), blk, 0, stream>>>(d_in[10], s2t, cD, cH, 0,
                                                              (long)cH * cD, (long)cD * cH, g_flag);
  transpose_k<<<dim3(cDH / 32, cD / 32, 1), blk, 0, stream>>>(d_in[13], a1t, cDH, cD, 0, 0, 0,
                                                              g_flag);
  owt_k<<<dim3(cD / 32, cD / 32, 4), blk, 0, stream>>>(d_in[17], owpair, g_flag);

  gates_k<<<cB / 4, blk, 0, stream>>>(g_xb, g_small + O_GW, g_small + O_GB, g_gates);
  bhist_k<<<cB / 256, blk, 0, stream>>>(sid, g_bh);
  bbase_k<<<1, 64, 0, stream>>>(g_bh, g_base, g_cum);
  bscat_k<<<cB / 256, blk, 0, stream>>>(sid, g_base, g_perm);

  if (BIG) {
    bf16* h4 = (bf16*)g_big;     // [16384,4096]
    float* sp = (float*)g_big;   // [16384,256] (after h4 dead)
    bf16* hspec = (bf16*)g_big;  // [16384,1024] (after sp dead)
    // GEMM1 (legacy engine — faster at K=512; r10 A/B)
    {
      GArgs a{};
      a.A = g_xb; a.lda = cD; a.Bt = w1t; a.ldb = cD;
      a.C = h4; a.ldc = 4096; a.M = cB; a.N = 4096; a.K = cD;
      a.bias = g_small + O_SB1; a.gates = g_gates;
      gemm_k<6, false, false, false><<<dim3(32, cB / 128), blk, 0, stream>>>(a);
    }
    // GEMM2 split-K=2 (g256 engine)
    if (use256) {
      G6Args a{};
      a.A = h4; a.lda = 4096; a.Bt = w2cat; a.ldb = 4096;
      a.C = g_ss; a.ldc = 1024; a.N = cD; a.K = 2048;
      g256_k<8><<<dim3(2, 64, 2), 512, 131072, stream>>>(a);
    } else {
      GArgs a{};
      a.A = h4; a.lda = 4096; a.Bt = w2cat; a.ldb = 4096;
      a.C = g_ss; a.ldc = 1024; a.M = cB; a.N = cD; a.K = 2048;
      a.eidx = 512;
      gemm_k<8, false, false, false, true><<<dim3(cD / 128, cB / 128, 2), blk, 0, stream>>>(a);
    }
    combine_k<<<cB * 64 / 256, blk, 0, stream>>>(g_ss, g_gates, g_small + O_SB2);
    {
      GArgs a{};
      a.A = g_ss; a.lda = 1024; a.Bt = a1t; a.ldb = cD;
      a.C = sp; a.ldc = cDH; a.M = cB; a.N = cDH; a.K = cD;
      gemm_k<3, false, false, false><<<dim3(cDH / 128, cB / 128), blk, 0, stream>>>(a);
    }
    scenpart_k<<<dim3(cS, 8), blk, 0, stream>>>(g_small + O_EMB, g_small + O_AW1, g_small + O_AB1,
                                                g_scp);
    wsel_k<<<cB / 4, blk, 0, stream>>>(sp, g_scp, g_small + O_AW2, sid, g_wsel);
    {
      GArgs a{};
      a.A = g_xb; a.lda = cD; a.Bt = s1t; a.ldb = cD; a.bt_stride = (long)cH * cD;
      a.C = hspec; a.ldc = cH; a.M = cB; a.N = cH; a.K = cD;
      a.bias = g_small + O_PB1; a.bias_stride = cH;
      a.perm = g_perm; a.cum = g_cum;
      gemm_k<1, true, true, false><<<dim3(cH / 128, cB / 128, cS), blk, 0, stream>>>(a);
    }
    {
      GArgs a{};
      a.A = hspec; a.lda = cH; a.Bt = s2t; a.ldb = cH; a.bt_stride = (long)cD * cH;
      a.C = g_ss + 512; a.ldc = 1024; a.M = cB; a.N = cD; a.K = cH;
      a.bias = g_small + O_PB2; a.bias_stride = cD;
      a.perm = g_perm; a.cum = g_cum;
      gemm_k<4, true, false, true><<<dim3(cD / 128, cB / 128, cS), blk, 0, stream>>>(a);
    }
    // merged P1+out (g256 engine)
    if (use256) {
      G6Args a{};
      a.A = g_ss; a.lda = 1024; a.Bt = owpair; a.ldb = 1024;
      a.C = d_out; a.ldc = cD; a.N = 1024; a.K = 1024;
      a.bias = g_small + O_OB; a.wsel = g_wsel; a.dflag = g_flag;
      g256_k<9><<<dim3(4, 64), 512, 131072, stream>>>(a);
    } else {
      GArgs a{};
      a.A = g_ss; a.lda = 1024; a.Bt = owpair; a.ldb = 1024;
      a.C = d_out; a.ldc = cD; a.M = cB; a.N = 1024; a.K = 1024;
      a.bias = g_small + O_OB; a.wsel = g_wsel; a.dflag = g_flag;
      gemm_k<9, false, false, false><<<dim3(8, cB / 128), blk, 0, stream>>>(a);
    }
  } else {
    // fallback: sequential-expert structure inside 68MB scratch
    float* f32a = (float*)g_big;            // [16384,512] f32
    bf16* hbuf = (bf16*)(g_big + 34 * MB);  // [16384,1024] bf16
    for (int e = 0; e < cE; e++) {
      GArgs a1{};
      a1.A = g_xb; a1.lda = cD; a1.Bt = w1t + (size_t)e * cH * cD; a1.ldb = cD;
      a1.C = hbuf; a1.ldc = cH; a1.M = cB; a1.N = cH; a1.K = cD;
      a1.bias = g_small + O_SB1 + e * cH;
      gemm_k<1, false, false, false><<<dim3(cH / 128, cB / 128), blk, 0, stream>>>(a1);
      GArgs a2{};
      a2.A = hbuf; a2.lda = cH; a2.Bt = w2cat + (size_t)e * 1024; a2.ldb = 4096;
      a2.C = f32a; a2.ldc = cD; a2.M = cB; a2.N = cD; a2.K = cH;
      a2.bias = g_small + O_SB2 + e * cD; a2.gates = g_gates; a2.eidx = e;
      gemm_k<2, false, false, false><<<dim3(cD / 128, cB / 128), blk, 0, stream>>>(a2);
    }
    cvt_shared_k<<<cB * 128 / 256, blk, 0, stream>>>(f32a, g_ss);
    {
      GArgs a{};
      a.A = g_xb; a.lda = cD; a.Bt = s1t; a.ldb = cD; a.bt_stride = (long)cH * cD;
      a.C = hbuf; a.ldc = cH; a.M = cB; a.N = cH; a.K = cD;
      a.bias = g_small + O_PB1; a.bias_stride = cH;
      a.perm = g_perm; a.cum = g_cum;
      gemm_k<1, true, true, false><<<dim3(cH / 128, cB / 128, cS), blk, 0, stream>>>(a);
    }
    {
      GArgs a{};
      a.A = hbuf; a.lda = cH; a.Bt = s2t; a.ldb = cH; a.bt_stride = (long)cD * cH;
      a.C = g_ss + 512; a.ldc = 1024; a.M = cB; a.N = cD; a.K = cH;
      a.bias = g_small + O_PB2; a.bias_stride = cD;
      a.perm = g_perm; a.cum = g_cum;
      gemm_k<4, true, false, true><<<dim3(cD / 128, cB / 128, cS), blk, 0, stream>>>(a);
    }
    {
      GArgs a{};
      a.A = g_ss; a.lda = 1024; a.Bt = a1t; a.ldb = cD;
      a.C = f32a; a.ldc = cDH; a.M = cB; a.N = cDH; a.K = cD;
      gemm_k<3, false, false, false><<<dim3(cDH / 128, cB / 128), blk, 0, stream>>>(a);
    }
    scenpart_k<<<dim3(cS, 8), blk, 0, stream>>>(g_small + O_EMB, g_small + O_AW1, g_small + O_AB1,
                                                g_scp);
    wsel_k<<<cB / 4, blk, 0, stream>>>(f32a, g_scp, g_small + O_AW2, sid, g_wsel);
    {
      GArgs a{};
      a.A = g_ss; a.lda = 1024; a.Bt = owpair; a.ldb = 1024;
      a.C = d_out; a.ldc = cD; a.M = cB; a.N = 1024; a.K = 1024;
      a.bias = g_small + O_OB; a.wsel = g_wsel; a.dflag = g_flag;
      gemm_k<9, false, false, false><<<dim3(8, cB / 128), blk, 0, stream>>>(a);
    }
  }
}